// Round 4
// baseline (683.093 us; speedup 1.0000x reference)
//
#include <hip/hip_runtime.h>

#define D 64
#define NREL 3
#define SRC_MASK 0x07FFFFFF
#define NPB 64  // nodes per bucket for 2-phase reorder

// ---------------- transform: hr[r][n][od] = sum_k x[n][k]*W[r][k][od] ----------------
// 192 threads; block covers 64 nodes x 192 outputs (3 rels x 64 od).
// Thread computes an 8-node x 8-output register tile -> ~1 B LDS traffic per FMA.
__global__ __launch_bounds__(192) void transform_kernel(
    const float* __restrict__ x, const float* __restrict__ W,
    float* __restrict__ hr, int n_nodes) {
  __shared__ float xs[64][68];          // padded: staging writes conflict-free
  __shared__ float wl[NREL * 64 * 64];  // 48 KB
  const int tid = threadIdx.x;
  const int base = blockIdx.x * 64;
  const int nrows = min(64, n_nodes - base);

  for (int idx = tid; idx < 3072; idx += 192) {  // 12288 floats as float4
    *reinterpret_cast<float4*>(&wl[idx * 4]) =
        *reinterpret_cast<const float4*>(&W[idx * 4]);
  }
  for (int idx = tid; idx < 64 * 16; idx += 192) {
    const int n = idx >> 4;
    const int c = (idx & 15) * 4;
    float4 v = {0.f, 0.f, 0.f, 0.f};
    if (n < nrows) v = *reinterpret_cast<const float4*>(&x[(long)(base + n) * 64 + c]);
    *reinterpret_cast<float4*>(&xs[n][c]) = v;
  }
  __syncthreads();

  const int jt = tid % 24;  // j0 = jt*8 in [0,192): never crosses a relation boundary
  const int nt = tid / 24;  // 8 n-tiles of 8 nodes
  const int j0 = jt * 8;
  const int r = j0 >> 6;
  const int od0 = j0 & 63;
  const int n0 = nt * 8;
  const float* wrow = &wl[r * 4096];

  float acc[8][8];
#pragma unroll
  for (int i = 0; i < 8; ++i)
#pragma unroll
    for (int j = 0; j < 8; ++j) acc[i][j] = 0.f;

#pragma unroll 2
  for (int k = 0; k < 64; ++k) {
    float a[8];
#pragma unroll
    for (int i = 0; i < 8; ++i) a[i] = xs[n0 + i][k];  // <=4 distinct addrs/wave
    const float4 b0 = *reinterpret_cast<const float4*>(&wrow[k * 64 + od0]);
    const float4 b1 = *reinterpret_cast<const float4*>(&wrow[k * 64 + od0 + 4]);
    const float bb[8] = {b0.x, b0.y, b0.z, b0.w, b1.x, b1.y, b1.z, b1.w};
#pragma unroll
    for (int i = 0; i < 8; ++i)
#pragma unroll
      for (int j = 0; j < 8; ++j) acc[i][j] += a[i] * bb[j];
  }

#pragma unroll
  for (int i = 0; i < 8; ++i) {
    const int n = n0 + i;
    if (n < nrows) {
      float4 o0 = {acc[i][0], acc[i][1], acc[i][2], acc[i][3]};
      float4 o1 = {acc[i][4], acc[i][5], acc[i][6], acc[i][7]};
      float* dst = &hr[((long)r * n_nodes + base + n) * 64 + od0];
      *reinterpret_cast<float4*>(dst) = o0;
      *reinterpret_cast<float4*>(dst + 4) = o1;
    }
  }
}

// ---------------- CSR build ----------------
__global__ __launch_bounds__(256) void hist_kernel(
    const int* __restrict__ dst, int* __restrict__ deg, int n_edges) {
  const int e = blockIdx.x * 256 + threadIdx.x;
  if (e < n_edges) atomicAdd(&deg[dst[e]], 1);
}

__global__ __launch_bounds__(256) void scan1_kernel(
    const int* __restrict__ deg, int* __restrict__ offs,
    int* __restrict__ partials, int n_nodes) {
  __shared__ int ssum[256];
  const int t = threadIdx.x;
  const int base = blockIdx.x * 1024 + t * 4;
  int v0 = (base + 0 < n_nodes) ? deg[base + 0] : 0;
  int v1 = (base + 1 < n_nodes) ? deg[base + 1] : 0;
  int v2 = (base + 2 < n_nodes) ? deg[base + 2] : 0;
  int v3 = (base + 3 < n_nodes) ? deg[base + 3] : 0;
  const int lsum = v0 + v1 + v2 + v3;
  ssum[t] = lsum;
  __syncthreads();
  for (int off = 1; off < 256; off <<= 1) {
    const int add = (t >= off) ? ssum[t - off] : 0;
    __syncthreads();
    ssum[t] += add;
    __syncthreads();
  }
  const int excl = ssum[t] - lsum;
  if (base + 0 < n_nodes) offs[base + 0] = excl;
  if (base + 1 < n_nodes) offs[base + 1] = excl + v0;
  if (base + 2 < n_nodes) offs[base + 2] = excl + v0 + v1;
  if (base + 3 < n_nodes) offs[base + 3] = excl + v0 + v1 + v2;
  if (t == 255) partials[blockIdx.x] = ssum[255];
}

__global__ __launch_bounds__(256) void scan2_kernel(int* __restrict__ partials,
                                                    int n_chunks) {
  __shared__ int s[256];
  const int t = threadIdx.x;
  const int v = (t < n_chunks) ? partials[t] : 0;
  s[t] = v;
  __syncthreads();
  for (int off = 1; off < 256; off <<= 1) {
    const int add = (t >= off) ? s[t - off] : 0;
    __syncthreads();
    s[t] += add;
    __syncthreads();
  }
  if (t < n_chunks) partials[t] = s[t] - v;
}

__global__ __launch_bounds__(256) void scan3_kernel(
    int* __restrict__ offs, const int* __restrict__ partials, int n_nodes) {
  const int i = blockIdx.x * 256 + threadIdx.x;
  if (i < n_nodes) offs[i] += partials[i >> 10];
}

// Phase A: append edge payload into its dst-bucket's final CSR region (unordered).
__global__ __launch_bounds__(256) void reorderA_kernel(
    const int* __restrict__ src, const int* __restrict__ dst,
    const int* __restrict__ rel, const float* __restrict__ norm,
    const int* __restrict__ offs, int* __restrict__ bcur,
    int2* __restrict__ tmpbuf, unsigned char* __restrict__ tmpd, int n_edges) {
  const int e = blockIdx.x * 256 + threadIdx.x;
  if (e >= n_edges) return;
  const int d = dst[e];
  const int b = d >> 6;  // NPB = 64
  const int pos = offs[b << 6] + atomicAdd(&bcur[b], 1);
  tmpbuf[pos] = make_int2(src[e] | (rel[e] << 27), __float_as_int(norm[e]));
  tmpd[pos] = (unsigned char)(d & 63);
}

// Phase B: within each bucket region (L2-hot, ~6 KB), place edges at exact CSR pos.
__global__ __launch_bounds__(256) void reorderB_kernel(
    const int2* __restrict__ tmpbuf, const unsigned char* __restrict__ tmpd,
    const int* __restrict__ offs, int* __restrict__ cursor,
    int2* __restrict__ edgebuf, int n_nodes, int n_edges) {
  const int b = blockIdx.x;
  const int lo = offs[b << 6];
  const int nb = (b + 1) << 6;
  const int hi = (nb >= n_nodes) ? n_edges : offs[nb];
  for (int i = lo + threadIdx.x; i < hi; i += 256) {
    const int d = (b << 6) + tmpd[i];
    const int p = offs[d] + atomicAdd(&cursor[d], 1);
    edgebuf[p] = tmpbuf[i];
  }
}

// ---------------- fused gather + skip + relu ----------------
__global__ __launch_bounds__(256) void gather_kernel(
    const float* __restrict__ hr, const int2* __restrict__ edgebuf,
    const int* __restrict__ offs, const int* __restrict__ deg,
    const float* __restrict__ skip, float* __restrict__ out,
    int n_nodes) {
  const long gid = (long)blockIdx.x * 256 + threadIdx.x;
  const int n = (int)(gid >> 4);
  if (n >= n_nodes) return;
  const int c = (int)(gid & 15) * 4;

  const int beg = offs[n];
  const int cnt = deg[n];

  float4 acc0 = {0.f, 0.f, 0.f, 0.f};
  float4 acc1 = {0.f, 0.f, 0.f, 0.f};
  int i = 0;
  for (; i + 1 < cnt; i += 2) {
    const int2 ea = edgebuf[beg + i];
    const int2 eb = edgebuf[beg + i + 1];
    const int sa = ea.x & SRC_MASK;
    const int ra = ((unsigned)ea.x) >> 27;
    const int sb = eb.x & SRC_MASK;
    const int rb = ((unsigned)eb.x) >> 27;
    const float na = __int_as_float(ea.y);
    const float nb = __int_as_float(eb.y);
    const float4 va = *reinterpret_cast<const float4*>(
        &hr[((long)ra * n_nodes + sa) * 64 + c]);
    const float4 vb = *reinterpret_cast<const float4*>(
        &hr[((long)rb * n_nodes + sb) * 64 + c]);
    acc0.x += va.x * na; acc0.y += va.y * na; acc0.z += va.z * na; acc0.w += va.w * na;
    acc1.x += vb.x * nb; acc1.y += vb.y * nb; acc1.z += vb.z * nb; acc1.w += vb.w * nb;
  }
  if (i < cnt) {
    const int2 ea = edgebuf[beg + i];
    const int sa = ea.x & SRC_MASK;
    const int ra = ((unsigned)ea.x) >> 27;
    const float na = __int_as_float(ea.y);
    const float4 va = *reinterpret_cast<const float4*>(
        &hr[((long)ra * n_nodes + sa) * 64 + c]);
    acc0.x += va.x * na; acc0.y += va.y * na; acc0.z += va.z * na; acc0.w += va.w * na;
  }
  float4 a;
  a.x = acc0.x + acc1.x; a.y = acc0.y + acc1.y;
  a.z = acc0.z + acc1.z; a.w = acc0.w + acc1.w;
  if (skip != nullptr) {
    const float4 s = *reinterpret_cast<const float4*>(&skip[(long)n * 64 + c]);
    a.x += s.x; a.y += s.y; a.z += s.z; a.w += s.w;
  }
  a.x = fmaxf(a.x, 0.f); a.y = fmaxf(a.y, 0.f);
  a.z = fmaxf(a.z, 0.f); a.w = fmaxf(a.w, 0.f);
  *reinterpret_cast<float4*>(&out[(long)n * 64 + c]) = a;
}

// ---------------- heads ----------------
__global__ __launch_bounds__(256) void heads_kernel(
    const float* __restrict__ x, const float* __restrict__ Wa,
    const float* __restrict__ ba, const float* __restrict__ Wb,
    const float* __restrict__ bb, float* __restrict__ out, int n_nodes) {
  __shared__ float xs[64][65];
  __shared__ float wl[23][64];
  __shared__ float bl[23];
  const int tid = threadIdx.x;
  const int base = blockIdx.x * 64;

  for (int idx = tid; idx < 2 * 64; idx += 256) wl[idx >> 6][idx & 63] = Wa[idx];
  for (int idx = tid; idx < 21 * 64; idx += 256) wl[2 + (idx >> 6)][idx & 63] = Wb[idx];
  if (tid < 2) bl[tid] = ba[tid];
  else if (tid < 23) bl[tid] = bb[tid - 2];
  const int nrows = min(64, n_nodes - base);
  for (int idx = tid; idx < nrows * 64; idx += 256)
    xs[idx >> 6][idx & 63] = x[(long)base * 64 + idx];
  __syncthreads();

  for (int idx = tid; idx < nrows * 23; idx += 256) {
    const int n = idx / 23;
    const int s = idx % 23;
    float acc = 0.f;
#pragma unroll
    for (int k = 0; k < 64; ++k) acc += xs[n][k] * wl[s][k];
    acc += bl[s];
    const long node = base + n;
    if (s < 2) out[node * 2 + s] = acc;
    else out[(long)n_nodes * 2 + node * 21 + (s - 2)] = acc;
  }
}

static inline char* align_up(char* p, size_t a) {
  return (char*)(((uintptr_t)p + a - 1) & ~(uintptr_t)(a - 1));
}

extern "C" void kernel_launch(void* const* d_in, const int* in_sizes, int n_in,
                              void* d_out, int out_size, void* d_ws, size_t ws_size,
                              hipStream_t stream) {
  const float* v    = (const float*)d_in[0];
  const int*   esrc = (const int*)d_in[1];
  const int*   edst = (const int*)d_in[2];
  const int*   erel = (const int*)d_in[3];
  const float* norm = (const float*)d_in[4];
  const float* W1   = (const float*)d_in[5];
  const float* W2   = (const float*)d_in[6];
  const float* W3   = (const float*)d_in[7];
  const float* Wa   = (const float*)d_in[8];
  const float* ba   = (const float*)d_in[9];
  const float* Wb   = (const float*)d_in[10];
  const float* bb   = (const float*)d_in[11];

  const int nN = in_sizes[0] / D;  // 100000
  const int E  = in_sizes[1];      // 1200000
  const int nbuckets = (nN + NPB - 1) / NPB;

  // ---- workspace layout
  char* p = (char*)d_ws;
  float* hr   = (float*)p;            p += 3L * nN * D * sizeof(float);
  float* bufA = (float*)p;            p += (long)nN * D * sizeof(float);
  float* bufB = (float*)p;            p += (long)nN * D * sizeof(float);
  int* deg      = (int*)p;            p += (long)nN * sizeof(int);
  int* offs     = (int*)p;            p += (long)nN * sizeof(int);
  int* cursor   = (int*)p;            p += (long)nN * sizeof(int);
  int* bcur     = (int*)p;            p += (long)nbuckets * sizeof(int);
  int* partials = (int*)p;            p += 256 * sizeof(int);
  p = align_up(p, 16);
  int2* tmpbuf  = (int2*)p;           p += (long)E * sizeof(int2);
  int2* edgebuf = (int2*)p;           p += (long)E * sizeof(int2);
  unsigned char* tmpd = (unsigned char*)p;  p += (long)E;

  const int eblocks = (E + 255) / 256;
  const int tblocks = (nN + 63) / 64;
  const int gblocks = (int)(((long)nN * 16 + 255) / 256);
  const int nchunks = (nN + 1023) / 1024;

  // ---- CSR build (once per call)
  hipMemsetAsync(deg, 0, (size_t)nN * sizeof(int), stream);
  hipMemsetAsync(cursor, 0, (size_t)nN * sizeof(int), stream);
  hipMemsetAsync(bcur, 0, (size_t)nbuckets * sizeof(int), stream);
  hist_kernel<<<eblocks, 256, 0, stream>>>(edst, deg, E);
  scan1_kernel<<<nchunks, 256, 0, stream>>>(deg, offs, partials, nN);
  scan2_kernel<<<1, 256, 0, stream>>>(partials, nchunks);
  scan3_kernel<<<(nN + 255) / 256, 256, 0, stream>>>(offs, partials, nN);
  reorderA_kernel<<<eblocks, 256, 0, stream>>>(esrc, edst, erel, norm, offs, bcur,
                                               tmpbuf, tmpd, E);
  reorderB_kernel<<<nbuckets, 256, 0, stream>>>(tmpbuf, tmpd, offs, cursor,
                                                edgebuf, nN, E);

  // ---- layer 1: v -> bufA (no skip)
  transform_kernel<<<tblocks, 192, 0, stream>>>(v, W1, hr, nN);
  gather_kernel<<<gblocks, 256, 0, stream>>>(hr, edgebuf, offs, deg, nullptr, bufA, nN);

  // ---- layer 2: bufA -> bufB (skip)
  transform_kernel<<<tblocks, 192, 0, stream>>>(bufA, W2, hr, nN);
  gather_kernel<<<gblocks, 256, 0, stream>>>(hr, edgebuf, offs, deg, bufA, bufB, nN);

  // ---- layer 3: bufB -> bufA (skip)
  transform_kernel<<<tblocks, 192, 0, stream>>>(bufB, W3, hr, nN);
  gather_kernel<<<gblocks, 256, 0, stream>>>(hr, edgebuf, offs, deg, bufB, bufA, nN);

  // ---- heads
  heads_kernel<<<tblocks, 256, 0, stream>>>(bufA, Wa, ba, Wb, bb, (float*)d_out, nN);
}

// Round 5
// 480.138 us; speedup vs baseline: 1.4227x; 1.4227x over previous
//
#include <hip/hip_runtime.h>

#define D 64
#define NREL 3
#define SRC_MASK 0x07FFFFFF

typedef unsigned short bf16_t;

__device__ __forceinline__ float bf2f(unsigned int u16) {
  return __uint_as_float(u16 << 16);
}
__device__ __forceinline__ unsigned int f2bf(float f) {
  unsigned int x = __float_as_uint(f);
  return (x + 0x7fffu + ((x >> 16) & 1u)) >> 16;  // round-to-nearest-even
}

// ---------------- transform: hr[r][n][od] = sum_k x[n][k]*W[r][k][od] (bf16 out) ----
// 192 threads; block covers 64 nodes x 192 outputs (3 rels x 64 od).
// Thread computes an 8-node x 8-output register tile.
__global__ __launch_bounds__(192) void transform_kernel(
    const float* __restrict__ x, const float* __restrict__ W,
    bf16_t* __restrict__ hr, int n_nodes) {
  __shared__ float xs[64][68];          // padded staging
  __shared__ float wl[NREL * 64 * 64];  // 48 KB
  const int tid = threadIdx.x;
  const int base = blockIdx.x * 64;
  const int nrows = min(64, n_nodes - base);

  for (int idx = tid; idx < 3072; idx += 192) {
    *reinterpret_cast<float4*>(&wl[idx * 4]) =
        *reinterpret_cast<const float4*>(&W[idx * 4]);
  }
  for (int idx = tid; idx < 64 * 16; idx += 192) {
    const int n = idx >> 4;
    const int c = (idx & 15) * 4;
    float4 v = {0.f, 0.f, 0.f, 0.f};
    if (n < nrows) v = *reinterpret_cast<const float4*>(&x[(long)(base + n) * 64 + c]);
    *reinterpret_cast<float4*>(&xs[n][c]) = v;
  }
  __syncthreads();

  const int jt = tid % 24;  // j0 = jt*8 in [0,192): never crosses a relation boundary
  const int nt = tid / 24;  // 8 n-tiles of 8 nodes
  const int j0 = jt * 8;
  const int r = j0 >> 6;
  const int od0 = j0 & 63;
  const int n0 = nt * 8;
  const float* wrow = &wl[r * 4096];

  float acc[8][8];
#pragma unroll
  for (int i = 0; i < 8; ++i)
#pragma unroll
    for (int j = 0; j < 8; ++j) acc[i][j] = 0.f;

#pragma unroll 2
  for (int k = 0; k < 64; ++k) {
    float a[8];
#pragma unroll
    for (int i = 0; i < 8; ++i) a[i] = xs[n0 + i][k];
    const float4 b0 = *reinterpret_cast<const float4*>(&wrow[k * 64 + od0]);
    const float4 b1 = *reinterpret_cast<const float4*>(&wrow[k * 64 + od0 + 4]);
    const float bb[8] = {b0.x, b0.y, b0.z, b0.w, b1.x, b1.y, b1.z, b1.w};
#pragma unroll
    for (int i = 0; i < 8; ++i)
#pragma unroll
      for (int j = 0; j < 8; ++j) acc[i][j] += a[i] * bb[j];
  }

#pragma unroll
  for (int i = 0; i < 8; ++i) {
    const int n = n0 + i;
    if (n < nrows) {
      uint4 o;
      o.x = f2bf(acc[i][0]) | (f2bf(acc[i][1]) << 16);
      o.y = f2bf(acc[i][2]) | (f2bf(acc[i][3]) << 16);
      o.z = f2bf(acc[i][4]) | (f2bf(acc[i][5]) << 16);
      o.w = f2bf(acc[i][6]) | (f2bf(acc[i][7]) << 16);
      *reinterpret_cast<uint4*>(
          &hr[((long)r * n_nodes + base + n) * 64 + od0]) = o;
    }
  }
}

// ---------------- CSR build ----------------
__global__ __launch_bounds__(256) void hist_kernel(
    const int* __restrict__ dst, int* __restrict__ deg, int n_edges) {
  const int e = blockIdx.x * 256 + threadIdx.x;
  if (e < n_edges) atomicAdd(&deg[dst[e]], 1);
}

__global__ __launch_bounds__(256) void scan1_kernel(
    const int* __restrict__ deg, int* __restrict__ offs,
    int* __restrict__ partials, int n_nodes) {
  __shared__ int ssum[256];
  const int t = threadIdx.x;
  const int base = blockIdx.x * 1024 + t * 4;
  int v0 = (base + 0 < n_nodes) ? deg[base + 0] : 0;
  int v1 = (base + 1 < n_nodes) ? deg[base + 1] : 0;
  int v2 = (base + 2 < n_nodes) ? deg[base + 2] : 0;
  int v3 = (base + 3 < n_nodes) ? deg[base + 3] : 0;
  const int lsum = v0 + v1 + v2 + v3;
  ssum[t] = lsum;
  __syncthreads();
  for (int off = 1; off < 256; off <<= 1) {
    const int add = (t >= off) ? ssum[t - off] : 0;
    __syncthreads();
    ssum[t] += add;
    __syncthreads();
  }
  const int excl = ssum[t] - lsum;
  if (base + 0 < n_nodes) offs[base + 0] = excl;
  if (base + 1 < n_nodes) offs[base + 1] = excl + v0;
  if (base + 2 < n_nodes) offs[base + 2] = excl + v0 + v1;
  if (base + 3 < n_nodes) offs[base + 3] = excl + v0 + v1 + v2;
  if (t == 255) partials[blockIdx.x] = ssum[255];
}

__global__ __launch_bounds__(256) void scan2_kernel(int* __restrict__ partials,
                                                    int n_chunks) {
  __shared__ int s[256];
  const int t = threadIdx.x;
  const int v = (t < n_chunks) ? partials[t] : 0;
  s[t] = v;
  __syncthreads();
  for (int off = 1; off < 256; off <<= 1) {
    const int add = (t >= off) ? s[t - off] : 0;
    __syncthreads();
    s[t] += add;
    __syncthreads();
  }
  if (t < n_chunks) partials[t] = s[t] - v;
}

__global__ __launch_bounds__(256) void scan3_kernel(
    int* __restrict__ offs, const int* __restrict__ partials, int n_nodes) {
  const int i = blockIdx.x * 256 + threadIdx.x;
  if (i < n_nodes) offs[i] += partials[i >> 10];
}

// Single-phase reorder (per-node cursors: low contention, measured 82 us in R3).
__global__ __launch_bounds__(256) void reorder_kernel(
    const int* __restrict__ src, const int* __restrict__ dst,
    const int* __restrict__ rel, const float* __restrict__ norm,
    const int* __restrict__ offs, int* __restrict__ cursor,
    int2* __restrict__ edgebuf, int n_edges) {
  const int e = blockIdx.x * 256 + threadIdx.x;
  if (e >= n_edges) return;
  const int d = dst[e];
  const int pos = offs[d] + atomicAdd(&cursor[d], 1);
  edgebuf[pos] = make_int2(src[e] | (rel[e] << 27), __float_as_int(norm[e]));
}

// ---------------- fused gather + skip + relu (bf16 hr) ----------------
// 16 threads per node; each handles 4 features (one uint2 = 4 bf16 per edge).
__global__ __launch_bounds__(256) void gather_kernel(
    const bf16_t* __restrict__ hr, const int2* __restrict__ edgebuf,
    const int* __restrict__ offs, const int* __restrict__ deg,
    const float* __restrict__ skip, float* __restrict__ out,
    int n_nodes) {
  const long gid = (long)blockIdx.x * 256 + threadIdx.x;
  const int n = (int)(gid >> 4);
  if (n >= n_nodes) return;
  const int c = (int)(gid & 15) * 4;

  const int beg = offs[n];
  const int cnt = deg[n];

  float4 acc0 = {0.f, 0.f, 0.f, 0.f};
  float4 acc1 = {0.f, 0.f, 0.f, 0.f};
  int i = 0;
  for (; i + 1 < cnt; i += 2) {
    const int2 ea = edgebuf[beg + i];
    const int2 eb = edgebuf[beg + i + 1];
    const int sa = ea.x & SRC_MASK;
    const int ra = ((unsigned)ea.x) >> 27;
    const int sb = eb.x & SRC_MASK;
    const int rb = ((unsigned)eb.x) >> 27;
    const float na = __int_as_float(ea.y);
    const float nb = __int_as_float(eb.y);
    const uint2 va = *reinterpret_cast<const uint2*>(
        &hr[((long)ra * n_nodes + sa) * 64 + c]);
    const uint2 vb = *reinterpret_cast<const uint2*>(
        &hr[((long)rb * n_nodes + sb) * 64 + c]);
    acc0.x += bf2f(va.x & 0xffff) * na;
    acc0.y += bf2f(va.x >> 16) * na;
    acc0.z += bf2f(va.y & 0xffff) * na;
    acc0.w += bf2f(va.y >> 16) * na;
    acc1.x += bf2f(vb.x & 0xffff) * nb;
    acc1.y += bf2f(vb.x >> 16) * nb;
    acc1.z += bf2f(vb.y & 0xffff) * nb;
    acc1.w += bf2f(vb.y >> 16) * nb;
  }
  if (i < cnt) {
    const int2 ea = edgebuf[beg + i];
    const int sa = ea.x & SRC_MASK;
    const int ra = ((unsigned)ea.x) >> 27;
    const float na = __int_as_float(ea.y);
    const uint2 va = *reinterpret_cast<const uint2*>(
        &hr[((long)ra * n_nodes + sa) * 64 + c]);
    acc0.x += bf2f(va.x & 0xffff) * na;
    acc0.y += bf2f(va.x >> 16) * na;
    acc0.z += bf2f(va.y & 0xffff) * na;
    acc0.w += bf2f(va.y >> 16) * na;
  }
  float4 a;
  a.x = acc0.x + acc1.x; a.y = acc0.y + acc1.y;
  a.z = acc0.z + acc1.z; a.w = acc0.w + acc1.w;
  if (skip != nullptr) {
    const float4 s = *reinterpret_cast<const float4*>(&skip[(long)n * 64 + c]);
    a.x += s.x; a.y += s.y; a.z += s.z; a.w += s.w;
  }
  a.x = fmaxf(a.x, 0.f); a.y = fmaxf(a.y, 0.f);
  a.z = fmaxf(a.z, 0.f); a.w = fmaxf(a.w, 0.f);
  *reinterpret_cast<float4*>(&out[(long)n * 64 + c]) = a;
}

// ---------------- heads ----------------
__global__ __launch_bounds__(256) void heads_kernel(
    const float* __restrict__ x, const float* __restrict__ Wa,
    const float* __restrict__ ba, const float* __restrict__ Wb,
    const float* __restrict__ bb, float* __restrict__ out, int n_nodes) {
  __shared__ float xs[64][65];
  __shared__ float wl[23][64];
  __shared__ float bl[23];
  const int tid = threadIdx.x;
  const int base = blockIdx.x * 64;

  for (int idx = tid; idx < 2 * 64; idx += 256) wl[idx >> 6][idx & 63] = Wa[idx];
  for (int idx = tid; idx < 21 * 64; idx += 256) wl[2 + (idx >> 6)][idx & 63] = Wb[idx];
  if (tid < 2) bl[tid] = ba[tid];
  else if (tid < 23) bl[tid] = bb[tid - 2];
  const int nrows = min(64, n_nodes - base);
  for (int idx = tid; idx < nrows * 64; idx += 256)
    xs[idx >> 6][idx & 63] = x[(long)base * 64 + idx];
  __syncthreads();

  for (int idx = tid; idx < nrows * 23; idx += 256) {
    const int n = idx / 23;
    const int s = idx % 23;
    float acc = 0.f;
#pragma unroll
    for (int k = 0; k < 64; ++k) acc += xs[n][k] * wl[s][k];
    acc += bl[s];
    const long node = base + n;
    if (s < 2) out[node * 2 + s] = acc;
    else out[(long)n_nodes * 2 + node * 21 + (s - 2)] = acc;
  }
}

static inline char* align_up(char* p, size_t a) {
  return (char*)(((uintptr_t)p + a - 1) & ~(uintptr_t)(a - 1));
}

extern "C" void kernel_launch(void* const* d_in, const int* in_sizes, int n_in,
                              void* d_out, int out_size, void* d_ws, size_t ws_size,
                              hipStream_t stream) {
  const float* v    = (const float*)d_in[0];
  const int*   esrc = (const int*)d_in[1];
  const int*   edst = (const int*)d_in[2];
  const int*   erel = (const int*)d_in[3];
  const float* norm = (const float*)d_in[4];
  const float* W1   = (const float*)d_in[5];
  const float* W2   = (const float*)d_in[6];
  const float* W3   = (const float*)d_in[7];
  const float* Wa   = (const float*)d_in[8];
  const float* ba   = (const float*)d_in[9];
  const float* Wb   = (const float*)d_in[10];
  const float* bb   = (const float*)d_in[11];

  const int nN = in_sizes[0] / D;  // 100000
  const int E  = in_sizes[1];      // 1200000

  // ---- workspace layout
  char* p = (char*)d_ws;
  bf16_t* hr = (bf16_t*)p;            p += 3L * nN * D * sizeof(bf16_t);
  p = align_up(p, 16);
  float* bufA = (float*)p;            p += (long)nN * D * sizeof(float);
  float* bufB = (float*)p;            p += (long)nN * D * sizeof(float);
  int* deg      = (int*)p;            p += (long)nN * sizeof(int);
  int* offs     = (int*)p;            p += (long)nN * sizeof(int);
  int* cursor   = (int*)p;            p += (long)nN * sizeof(int);
  int* partials = (int*)p;            p += 256 * sizeof(int);
  p = align_up(p, 16);
  int2* edgebuf = (int2*)p;           p += (long)E * sizeof(int2);

  const int eblocks = (E + 255) / 256;
  const int tblocks = (nN + 63) / 64;
  const int gblocks = (int)(((long)nN * 16 + 255) / 256);
  const int nchunks = (nN + 1023) / 1024;

  // ---- CSR build (once per call)
  hipMemsetAsync(deg, 0, (size_t)nN * sizeof(int), stream);
  hipMemsetAsync(cursor, 0, (size_t)nN * sizeof(int), stream);
  hist_kernel<<<eblocks, 256, 0, stream>>>(edst, deg, E);
  scan1_kernel<<<nchunks, 256, 0, stream>>>(deg, offs, partials, nN);
  scan2_kernel<<<1, 256, 0, stream>>>(partials, nchunks);
  scan3_kernel<<<(nN + 255) / 256, 256, 0, stream>>>(offs, partials, nN);
  reorder_kernel<<<eblocks, 256, 0, stream>>>(esrc, edst, erel, norm, offs, cursor,
                                              edgebuf, E);

  // ---- layer 1: v -> bufA (no skip)
  transform_kernel<<<tblocks, 192, 0, stream>>>(v, W1, hr, nN);
  gather_kernel<<<gblocks, 256, 0, stream>>>(hr, edgebuf, offs, deg, nullptr, bufA, nN);

  // ---- layer 2: bufA -> bufB (skip)
  transform_kernel<<<tblocks, 192, 0, stream>>>(bufA, W2, hr, nN);
  gather_kernel<<<gblocks, 256, 0, stream>>>(hr, edgebuf, offs, deg, bufA, bufB, nN);

  // ---- layer 3: bufB -> bufA (skip)
  transform_kernel<<<tblocks, 192, 0, stream>>>(bufB, W3, hr, nN);
  gather_kernel<<<gblocks, 256, 0, stream>>>(hr, edgebuf, offs, deg, bufB, bufA, nN);

  // ---- heads
  heads_kernel<<<tblocks, 256, 0, stream>>>(bufA, Wa, ba, Wb, bb, (float*)d_out, nN);
}

// Round 6
// 434.089 us; speedup vs baseline: 1.5736x; 1.1061x over previous
//
#include <hip/hip_runtime.h>

#define D 64
#define NREL 3
#define SRC_MASK 0x07FFFFFF
#define ATHR 512
#define APT 8
#define ABLK (ATHR * APT)  // 4096 edges per binA block

typedef unsigned short bf16_t;

__device__ __forceinline__ float bf2f(unsigned int u16) {
  return __uint_as_float(u16 << 16);
}
__device__ __forceinline__ unsigned int f2bf(float f) {
  unsigned int x = __float_as_uint(f);
  return (x + 0x7fffu + ((x >> 16) & 1u)) >> 16;  // round-to-nearest-even
}

// ---------------- transform: hr[r][n][od] = sum_k x[n][k]*W[r][k][od] (bf16 out) ----
__global__ __launch_bounds__(192) void transform_kernel(
    const float* __restrict__ x, const float* __restrict__ W,
    bf16_t* __restrict__ hr, int n_nodes) {
  __shared__ float xs[64][68];
  __shared__ float wl[NREL * 64 * 64];
  const int tid = threadIdx.x;
  const int base = blockIdx.x * 64;
  const int nrows = min(64, n_nodes - base);

  for (int idx = tid; idx < 3072; idx += 192) {
    *reinterpret_cast<float4*>(&wl[idx * 4]) =
        *reinterpret_cast<const float4*>(&W[idx * 4]);
  }
  for (int idx = tid; idx < 64 * 16; idx += 192) {
    const int n = idx >> 4;
    const int c = (idx & 15) * 4;
    float4 v = {0.f, 0.f, 0.f, 0.f};
    if (n < nrows) v = *reinterpret_cast<const float4*>(&x[(long)(base + n) * 64 + c]);
    *reinterpret_cast<float4*>(&xs[n][c]) = v;
  }
  __syncthreads();

  const int jt = tid % 24;
  const int nt = tid / 24;
  const int j0 = jt * 8;
  const int r = j0 >> 6;
  const int od0 = j0 & 63;
  const int n0 = nt * 8;
  const float* wrow = &wl[r * 4096];

  float acc[8][8];
#pragma unroll
  for (int i = 0; i < 8; ++i)
#pragma unroll
    for (int j = 0; j < 8; ++j) acc[i][j] = 0.f;

#pragma unroll 2
  for (int k = 0; k < 64; ++k) {
    float a[8];
#pragma unroll
    for (int i = 0; i < 8; ++i) a[i] = xs[n0 + i][k];
    const float4 b0 = *reinterpret_cast<const float4*>(&wrow[k * 64 + od0]);
    const float4 b1 = *reinterpret_cast<const float4*>(&wrow[k * 64 + od0 + 4]);
    const float bb[8] = {b0.x, b0.y, b0.z, b0.w, b1.x, b1.y, b1.z, b1.w};
#pragma unroll
    for (int i = 0; i < 8; ++i)
#pragma unroll
      for (int j = 0; j < 8; ++j) acc[i][j] += a[i] * bb[j];
  }

#pragma unroll
  for (int i = 0; i < 8; ++i) {
    const int n = n0 + i;
    if (n < nrows) {
      uint4 o;
      o.x = f2bf(acc[i][0]) | (f2bf(acc[i][1]) << 16);
      o.y = f2bf(acc[i][2]) | (f2bf(acc[i][3]) << 16);
      o.z = f2bf(acc[i][4]) | (f2bf(acc[i][5]) << 16);
      o.w = f2bf(acc[i][6]) | (f2bf(acc[i][7]) << 16);
      *reinterpret_cast<uint4*>(
          &hr[((long)r * n_nodes + base + n) * 64 + od0]) = o;
    }
  }
}

// ---------------- CSR build ----------------
__global__ __launch_bounds__(256) void hist_kernel(
    const int* __restrict__ dst, int* __restrict__ deg, int n_edges) {
  const int e = blockIdx.x * 256 + threadIdx.x;
  if (e < n_edges) atomicAdd(&deg[dst[e]], 1);
}

__global__ __launch_bounds__(256) void scan1_kernel(
    const int* __restrict__ deg, int* __restrict__ offs,
    int* __restrict__ partials, int n_nodes) {
  __shared__ int ssum[256];
  const int t = threadIdx.x;
  const int base = blockIdx.x * 1024 + t * 4;
  int v0 = (base + 0 < n_nodes) ? deg[base + 0] : 0;
  int v1 = (base + 1 < n_nodes) ? deg[base + 1] : 0;
  int v2 = (base + 2 < n_nodes) ? deg[base + 2] : 0;
  int v3 = (base + 3 < n_nodes) ? deg[base + 3] : 0;
  const int lsum = v0 + v1 + v2 + v3;
  ssum[t] = lsum;
  __syncthreads();
  for (int off = 1; off < 256; off <<= 1) {
    const int add = (t >= off) ? ssum[t - off] : 0;
    __syncthreads();
    ssum[t] += add;
    __syncthreads();
  }
  const int excl = ssum[t] - lsum;
  if (base + 0 < n_nodes) offs[base + 0] = excl;
  if (base + 1 < n_nodes) offs[base + 1] = excl + v0;
  if (base + 2 < n_nodes) offs[base + 2] = excl + v0 + v1;
  if (base + 3 < n_nodes) offs[base + 3] = excl + v0 + v1 + v2;
  if (t == 255) partials[blockIdx.x] = ssum[255];
}

__global__ __launch_bounds__(256) void scan2_kernel(int* __restrict__ partials,
                                                    int n_chunks) {
  __shared__ int s[256];
  const int t = threadIdx.x;
  const int v = (t < n_chunks) ? partials[t] : 0;
  s[t] = v;
  __syncthreads();
  for (int off = 1; off < 256; off <<= 1) {
    const int add = (t >= off) ? s[t - off] : 0;
    __syncthreads();
    s[t] += add;
    __syncthreads();
  }
  if (t < n_chunks) partials[t] = s[t] - v;
}

__global__ __launch_bounds__(256) void scan3_kernel(
    int* __restrict__ offs, const int* __restrict__ partials, int n_nodes) {
  const int i = blockIdx.x * 256 + threadIdx.x;
  if (i < n_nodes) offs[i] += partials[i >> 10];
}

// Phase A: bin edges by dst>>8 into the bucket's final CSR range (unordered within
// bucket). Per-block LDS counting -> ONE global reserve atomic per (block,bucket);
// contiguous append runs -> near-full write lines.
__global__ __launch_bounds__(ATHR) void binA_kernel(
    const int* __restrict__ src, const int* __restrict__ dst,
    const int* __restrict__ rel, const float* __restrict__ norm,
    const int* __restrict__ offs, int* __restrict__ bcur,
    int2* __restrict__ binpay, unsigned char* __restrict__ bindst,
    int n_edges, int nb) {
  __shared__ int cnt[400];
  __shared__ int basea[400];
  const int t = threadIdx.x;
  const long e0 = (long)blockIdx.x * ABLK;

  for (int b = t; b < nb; b += ATHR) cnt[b] = 0;
  __syncthreads();

  int2 pay[APT];
  int bk[APT], slot[APT], dlo[APT];
#pragma unroll
  for (int i = 0; i < APT; ++i) {
    const long e = e0 + t + (long)i * ATHR;
    if (e < n_edges) {
      const int d = dst[e];
      bk[i] = d >> 8;
      dlo[i] = d & 255;
      pay[i] = make_int2(src[e] | (rel[e] << 27), __float_as_int(norm[e]));
      slot[i] = atomicAdd(&cnt[bk[i]], 1);
    } else {
      bk[i] = -1;
    }
  }
  __syncthreads();

  for (int b = t; b < nb; b += ATHR) {
    const int c = cnt[b];
    basea[b] = c ? (offs[b << 8] + atomicAdd(&bcur[b], c)) : 0;
  }
  __syncthreads();

#pragma unroll
  for (int i = 0; i < APT; ++i) {
    if (bk[i] >= 0) {
      const int pos = basea[bk[i]] + slot[i];
      binpay[pos] = pay[i];
      bindst[pos] = (unsigned char)dlo[i];
    }
  }
}

// Phase B: one block per bucket; scatter within the bucket's L2-resident CSR
// region to exact per-node position using LDS cursors (no global atomics).
__global__ __launch_bounds__(256) void binB_kernel(
    const int2* __restrict__ binpay, const unsigned char* __restrict__ bindst,
    const int* __restrict__ offs, int2* __restrict__ edgebuf,
    int n_nodes, int n_edges) {
  __shared__ int lcnt[256];
  const int b = blockIdx.x;
  const int t = threadIdx.x;
  lcnt[t] = 0;
  __syncthreads();
  const int start = offs[b << 8];
  const int nbase = (b + 1) << 8;
  const int end = (nbase >= n_nodes) ? n_edges : offs[nbase];
  for (int i = start + t; i < end; i += 256) {
    const int2 pay = binpay[i];
    const int dl = bindst[i];
    const int pos = offs[(b << 8) + dl] + atomicAdd(&lcnt[dl], 1);
    edgebuf[pos] = pay;
  }
}

// ---------------- fused gather + skip + relu (bf16 hr), 4-deep MLP ----------------
__global__ __launch_bounds__(256) void gather_kernel(
    const bf16_t* __restrict__ hr, const int2* __restrict__ edgebuf,
    const int* __restrict__ offs, const int* __restrict__ deg,
    const float* __restrict__ skip, float* __restrict__ out,
    int n_nodes) {
  const long gid = (long)blockIdx.x * 256 + threadIdx.x;
  const int n = (int)(gid >> 4);
  if (n >= n_nodes) return;
  const int c = (int)(gid & 15) * 4;

  const int beg = offs[n];
  const int cnt = deg[n];

  float4 acc0 = {0.f, 0.f, 0.f, 0.f};
  float4 acc1 = {0.f, 0.f, 0.f, 0.f};
  int i = 0;
  for (; i + 3 < cnt; i += 4) {
    const int2 e0 = edgebuf[beg + i];
    const int2 e1 = edgebuf[beg + i + 1];
    const int2 e2 = edgebuf[beg + i + 2];
    const int2 e3 = edgebuf[beg + i + 3];
    const uint2 v0 = *reinterpret_cast<const uint2*>(
        &hr[((long)(((unsigned)e0.x) >> 27) * n_nodes + (e0.x & SRC_MASK)) * 64 + c]);
    const uint2 v1 = *reinterpret_cast<const uint2*>(
        &hr[((long)(((unsigned)e1.x) >> 27) * n_nodes + (e1.x & SRC_MASK)) * 64 + c]);
    const uint2 v2 = *reinterpret_cast<const uint2*>(
        &hr[((long)(((unsigned)e2.x) >> 27) * n_nodes + (e2.x & SRC_MASK)) * 64 + c]);
    const uint2 v3 = *reinterpret_cast<const uint2*>(
        &hr[((long)(((unsigned)e3.x) >> 27) * n_nodes + (e3.x & SRC_MASK)) * 64 + c]);
    const float n0 = __int_as_float(e0.y), n1 = __int_as_float(e1.y);
    const float n2 = __int_as_float(e2.y), n3 = __int_as_float(e3.y);
    acc0.x += bf2f(v0.x & 0xffff) * n0; acc0.y += bf2f(v0.x >> 16) * n0;
    acc0.z += bf2f(v0.y & 0xffff) * n0; acc0.w += bf2f(v0.y >> 16) * n0;
    acc1.x += bf2f(v1.x & 0xffff) * n1; acc1.y += bf2f(v1.x >> 16) * n1;
    acc1.z += bf2f(v1.y & 0xffff) * n1; acc1.w += bf2f(v1.y >> 16) * n1;
    acc0.x += bf2f(v2.x & 0xffff) * n2; acc0.y += bf2f(v2.x >> 16) * n2;
    acc0.z += bf2f(v2.y & 0xffff) * n2; acc0.w += bf2f(v2.y >> 16) * n2;
    acc1.x += bf2f(v3.x & 0xffff) * n3; acc1.y += bf2f(v3.x >> 16) * n3;
    acc1.z += bf2f(v3.y & 0xffff) * n3; acc1.w += bf2f(v3.y >> 16) * n3;
  }
  for (; i < cnt; ++i) {
    const int2 ea = edgebuf[beg + i];
    const float na = __int_as_float(ea.y);
    const uint2 va = *reinterpret_cast<const uint2*>(
        &hr[((long)(((unsigned)ea.x) >> 27) * n_nodes + (ea.x & SRC_MASK)) * 64 + c]);
    acc0.x += bf2f(va.x & 0xffff) * na; acc0.y += bf2f(va.x >> 16) * na;
    acc0.z += bf2f(va.y & 0xffff) * na; acc0.w += bf2f(va.y >> 16) * na;
  }
  float4 a;
  a.x = acc0.x + acc1.x; a.y = acc0.y + acc1.y;
  a.z = acc0.z + acc1.z; a.w = acc0.w + acc1.w;
  if (skip != nullptr) {
    const float4 s = *reinterpret_cast<const float4*>(&skip[(long)n * 64 + c]);
    a.x += s.x; a.y += s.y; a.z += s.z; a.w += s.w;
  }
  a.x = fmaxf(a.x, 0.f); a.y = fmaxf(a.y, 0.f);
  a.z = fmaxf(a.z, 0.f); a.w = fmaxf(a.w, 0.f);
  *reinterpret_cast<float4*>(&out[(long)n * 64 + c]) = a;
}

// ---------------- heads ----------------
__global__ __launch_bounds__(256) void heads_kernel(
    const float* __restrict__ x, const float* __restrict__ Wa,
    const float* __restrict__ ba, const float* __restrict__ Wb,
    const float* __restrict__ bb, float* __restrict__ out, int n_nodes) {
  __shared__ float xs[64][65];
  __shared__ float wl[23][64];
  __shared__ float bl[23];
  const int tid = threadIdx.x;
  const int base = blockIdx.x * 64;

  for (int idx = tid; idx < 2 * 64; idx += 256) wl[idx >> 6][idx & 63] = Wa[idx];
  for (int idx = tid; idx < 21 * 64; idx += 256) wl[2 + (idx >> 6)][idx & 63] = Wb[idx];
  if (tid < 2) bl[tid] = ba[tid];
  else if (tid < 23) bl[tid] = bb[tid - 2];
  const int nrows = min(64, n_nodes - base);
  for (int idx = tid; idx < nrows * 64; idx += 256)
    xs[idx >> 6][idx & 63] = x[(long)base * 64 + idx];
  __syncthreads();

  for (int idx = tid; idx < nrows * 23; idx += 256) {
    const int n = idx / 23;
    const int s = idx % 23;
    float acc = 0.f;
#pragma unroll
    for (int k = 0; k < 64; ++k) acc += xs[n][k] * wl[s][k];
    acc += bl[s];
    const long node = base + n;
    if (s < 2) out[node * 2 + s] = acc;
    else out[(long)n_nodes * 2 + node * 21 + (s - 2)] = acc;
  }
}

static inline char* align_up(char* p, size_t a) {
  return (char*)(((uintptr_t)p + a - 1) & ~(uintptr_t)(a - 1));
}

extern "C" void kernel_launch(void* const* d_in, const int* in_sizes, int n_in,
                              void* d_out, int out_size, void* d_ws, size_t ws_size,
                              hipStream_t stream) {
  const float* v    = (const float*)d_in[0];
  const int*   esrc = (const int*)d_in[1];
  const int*   edst = (const int*)d_in[2];
  const int*   erel = (const int*)d_in[3];
  const float* norm = (const float*)d_in[4];
  const float* W1   = (const float*)d_in[5];
  const float* W2   = (const float*)d_in[6];
  const float* W3   = (const float*)d_in[7];
  const float* Wa   = (const float*)d_in[8];
  const float* ba   = (const float*)d_in[9];
  const float* Wb   = (const float*)d_in[10];
  const float* bb   = (const float*)d_in[11];

  const int nN = in_sizes[0] / D;  // 100000
  const int E  = in_sizes[1];      // 1200000
  const int nb = (nN + 255) >> 8;  // 256-node buckets

  // ---- workspace layout
  char* p = (char*)d_ws;
  bf16_t* hr = (bf16_t*)p;            p += 3L * nN * D * sizeof(bf16_t);
  p = align_up(p, 16);
  float* bufA = (float*)p;            p += (long)nN * D * sizeof(float);
  float* bufB = (float*)p;            p += (long)nN * D * sizeof(float);
  int* deg      = (int*)p;            p += (long)nN * sizeof(int);
  int* offs     = (int*)p;            p += (long)nN * sizeof(int);
  int* bcur     = (int*)p;            p += (long)nb * sizeof(int);
  int* partials = (int*)p;            p += 256 * sizeof(int);
  p = align_up(p, 16);
  int2* edgebuf = (int2*)p;           p += (long)E * sizeof(int2);
  int2* binpay  = (int2*)p;           p += (long)E * sizeof(int2);
  unsigned char* bindst = (unsigned char*)p;  p += (long)E;

  const int eblocks = (E + 255) / 256;
  const int tblocks = (nN + 63) / 64;
  const int gblocks = (int)(((long)nN * 16 + 255) / 256);
  const int nchunks = (nN + 1023) / 1024;
  const int ablocks = (E + ABLK - 1) / ABLK;

  // ---- CSR build (once per call)
  hipMemsetAsync(deg, 0, (size_t)nN * sizeof(int), stream);
  hipMemsetAsync(bcur, 0, (size_t)nb * sizeof(int), stream);
  hist_kernel<<<eblocks, 256, 0, stream>>>(edst, deg, E);
  scan1_kernel<<<nchunks, 256, 0, stream>>>(deg, offs, partials, nN);
  scan2_kernel<<<1, 256, 0, stream>>>(partials, nchunks);
  scan3_kernel<<<(nN + 255) / 256, 256, 0, stream>>>(offs, partials, nN);
  binA_kernel<<<ablocks, ATHR, 0, stream>>>(esrc, edst, erel, norm, offs, bcur,
                                            binpay, bindst, E, nb);
  binB_kernel<<<nb, 256, 0, stream>>>(binpay, bindst, offs, edgebuf, nN, E);

  // ---- layer 1: v -> bufA (no skip)
  transform_kernel<<<tblocks, 192, 0, stream>>>(v, W1, hr, nN);
  gather_kernel<<<gblocks, 256, 0, stream>>>(hr, edgebuf, offs, deg, nullptr, bufA, nN);

  // ---- layer 2: bufA -> bufB (skip)
  transform_kernel<<<tblocks, 192, 0, stream>>>(bufA, W2, hr, nN);
  gather_kernel<<<gblocks, 256, 0, stream>>>(hr, edgebuf, offs, deg, bufA, bufB, nN);

  // ---- layer 3: bufB -> bufA (skip)
  transform_kernel<<<tblocks, 192, 0, stream>>>(bufB, W3, hr, nN);
  gather_kernel<<<gblocks, 256, 0, stream>>>(hr, edgebuf, offs, deg, bufB, bufA, nN);

  // ---- heads
  heads_kernel<<<tblocks, 256, 0, stream>>>(bufA, Wa, ba, Wb, bb, (float*)d_out, nN);
}

// Round 9
// 391.979 us; speedup vs baseline: 1.7427x; 1.1074x over previous
//
#include <hip/hip_runtime.h>

#define D 64
#define NREL 3
#define SRC_MASK 0x07FFFFFF
#define ATHR 512
#define APT 8
#define ABLK (ATHR * APT)  // 4096 edges per binA block

typedef unsigned short bf16_t;

__device__ __forceinline__ float bf2f(unsigned int u16) {
  return __uint_as_float(u16 << 16);
}
__device__ __forceinline__ unsigned int f2bf(float f) {
  unsigned int x = __float_as_uint(f);
  return (x + 0x7fffu + ((x >> 16) & 1u)) >> 16;  // round-to-nearest-even
}

// ---------------- transform: hr[r][n][od] = sum_k x[n][k]*W[r][k][od] (bf16 out) ----
__global__ __launch_bounds__(192) void transform_kernel(
    const float* __restrict__ x, const float* __restrict__ W,
    bf16_t* __restrict__ hr, int n_nodes) {
  __shared__ float xs[64][68];
  __shared__ float wl[NREL * 64 * 64];
  const int tid = threadIdx.x;
  const int base = blockIdx.x * 64;
  const int nrows = min(64, n_nodes - base);

  for (int idx = tid; idx < 3072; idx += 192) {
    *reinterpret_cast<float4*>(&wl[idx * 4]) =
        *reinterpret_cast<const float4*>(&W[idx * 4]);
  }
  for (int idx = tid; idx < 64 * 16; idx += 192) {
    const int n = idx >> 4;
    const int c = (idx & 15) * 4;
    float4 v = {0.f, 0.f, 0.f, 0.f};
    if (n < nrows) v = *reinterpret_cast<const float4*>(&x[(long)(base + n) * 64 + c]);
    *reinterpret_cast<float4*>(&xs[n][c]) = v;
  }
  __syncthreads();

  const int jt = tid % 24;
  const int nt = tid / 24;
  const int j0 = jt * 8;
  const int r = j0 >> 6;
  const int od0 = j0 & 63;
  const int n0 = nt * 8;
  const float* wrow = &wl[r * 4096];

  float acc[8][8];
#pragma unroll
  for (int i = 0; i < 8; ++i)
#pragma unroll
    for (int j = 0; j < 8; ++j) acc[i][j] = 0.f;

#pragma unroll 2
  for (int k = 0; k < 64; ++k) {
    float a[8];
#pragma unroll
    for (int i = 0; i < 8; ++i) a[i] = xs[n0 + i][k];
    const float4 b0 = *reinterpret_cast<const float4*>(&wrow[k * 64 + od0]);
    const float4 b1 = *reinterpret_cast<const float4*>(&wrow[k * 64 + od0 + 4]);
    const float bb[8] = {b0.x, b0.y, b0.z, b0.w, b1.x, b1.y, b1.z, b1.w};
#pragma unroll
    for (int i = 0; i < 8; ++i)
#pragma unroll
      for (int j = 0; j < 8; ++j) acc[i][j] += a[i] * bb[j];
  }

#pragma unroll
  for (int i = 0; i < 8; ++i) {
    const int n = n0 + i;
    if (n < nrows) {
      uint4 o;
      o.x = f2bf(acc[i][0]) | (f2bf(acc[i][1]) << 16);
      o.y = f2bf(acc[i][2]) | (f2bf(acc[i][3]) << 16);
      o.z = f2bf(acc[i][4]) | (f2bf(acc[i][5]) << 16);
      o.w = f2bf(acc[i][6]) | (f2bf(acc[i][7]) << 16);
      *reinterpret_cast<uint4*>(
          &hr[((long)r * n_nodes + base + n) * 64 + od0]) = o;
    }
  }
}

// ---------------- CSR build ----------------
__global__ __launch_bounds__(256) void hist_kernel(
    const int* __restrict__ dst, int* __restrict__ deg, int n_edges) {
  const int e = blockIdx.x * 256 + threadIdx.x;
  if (e < n_edges) atomicAdd(&deg[dst[e]], 1);
}

__global__ __launch_bounds__(256) void scan1_kernel(
    const int* __restrict__ deg, int* __restrict__ offs,
    int* __restrict__ partials, int n_nodes) {
  __shared__ int ssum[256];
  const int t = threadIdx.x;
  const int base = blockIdx.x * 1024 + t * 4;
  int v0 = (base + 0 < n_nodes) ? deg[base + 0] : 0;
  int v1 = (base + 1 < n_nodes) ? deg[base + 1] : 0;
  int v2 = (base + 2 < n_nodes) ? deg[base + 2] : 0;
  int v3 = (base + 3 < n_nodes) ? deg[base + 3] : 0;
  const int lsum = v0 + v1 + v2 + v3;
  ssum[t] = lsum;
  __syncthreads();
  for (int off = 1; off < 256; off <<= 1) {
    const int add = (t >= off) ? ssum[t - off] : 0;
    __syncthreads();
    ssum[t] += add;
    __syncthreads();
  }
  const int excl = ssum[t] - lsum;
  if (base + 0 < n_nodes) offs[base + 0] = excl;
  if (base + 1 < n_nodes) offs[base + 1] = excl + v0;
  if (base + 2 < n_nodes) offs[base + 2] = excl + v0 + v1;
  if (base + 3 < n_nodes) offs[base + 3] = excl + v0 + v1 + v2;
  if (t == 255) partials[blockIdx.x] = ssum[255];
}

__global__ __launch_bounds__(256) void scan2_kernel(int* __restrict__ partials,
                                                    int n_chunks) {
  __shared__ int s[256];
  const int t = threadIdx.x;
  const int v = (t < n_chunks) ? partials[t] : 0;
  s[t] = v;
  __syncthreads();
  for (int off = 1; off < 256; off <<= 1) {
    const int add = (t >= off) ? s[t - off] : 0;
    __syncthreads();
    s[t] += add;
    __syncthreads();
  }
  if (t < n_chunks) partials[t] = s[t] - v;
}

__global__ __launch_bounds__(256) void scan3_kernel(
    int* __restrict__ offs, const int* __restrict__ partials, int n_nodes) {
  const int i = blockIdx.x * 256 + threadIdx.x;
  if (i < n_nodes) offs[i] += partials[i >> 10];
}

// Phase A: bin edges by dst>>8 into the bucket's final CSR range (unordered within
// bucket). Per-block LDS counting -> ONE global reserve atomic per (block,bucket).
__global__ __launch_bounds__(ATHR) void binA_kernel(
    const int* __restrict__ src, const int* __restrict__ dst,
    const int* __restrict__ rel, const float* __restrict__ norm,
    const int* __restrict__ offs, int* __restrict__ bcur,
    int2* __restrict__ binpay, unsigned char* __restrict__ bindst,
    int n_edges, int nb) {
  __shared__ int cnt[400];
  __shared__ int basea[400];
  const int t = threadIdx.x;
  const long e0 = (long)blockIdx.x * ABLK;

  for (int b = t; b < nb; b += ATHR) cnt[b] = 0;
  __syncthreads();

  int2 pay[APT];
  int bk[APT], slot[APT], dlo[APT];
#pragma unroll
  for (int i = 0; i < APT; ++i) {
    const long e = e0 + t + (long)i * ATHR;
    if (e < n_edges) {
      const int d = dst[e];
      bk[i] = d >> 8;
      dlo[i] = d & 255;
      pay[i] = make_int2(src[e] | (rel[e] << 27), __float_as_int(norm[e]));
      slot[i] = atomicAdd(&cnt[bk[i]], 1);
    } else {
      bk[i] = -1;
    }
  }
  __syncthreads();

  for (int b = t; b < nb; b += ATHR) {
    const int c = cnt[b];
    basea[b] = c ? (offs[b << 8] + atomicAdd(&bcur[b], c)) : 0;
  }
  __syncthreads();

#pragma unroll
  for (int i = 0; i < APT; ++i) {
    if (bk[i] >= 0) {
      const int pos = basea[bk[i]] + slot[i];
      binpay[pos] = pay[i];
      bindst[pos] = (unsigned char)dlo[i];
    }
  }
}

// Phase B: one block per bucket; scatter within the bucket's L2-resident CSR
// region to exact per-node position using LDS cursors (no global atomics).
__global__ __launch_bounds__(256) void binB_kernel(
    const int2* __restrict__ binpay, const unsigned char* __restrict__ bindst,
    const int* __restrict__ offs, int2* __restrict__ edgebuf,
    int n_nodes, int n_edges) {
  __shared__ int lcnt[256];
  const int b = blockIdx.x;
  const int t = threadIdx.x;
  lcnt[t] = 0;
  __syncthreads();
  const int start = offs[b << 8];
  const int nbase = (b + 1) << 8;
  const int end = (nbase >= n_nodes) ? n_edges : offs[nbase];
  for (int i = start + t; i < end; i += 256) {
    const int2 pay = binpay[i];
    const int dl = bindst[i];
    const int pos = offs[(b << 8) + dl] + atomicAdd(&lcnt[dl], 1);
    edgebuf[pos] = pay;
  }
}

// ---------------- fused gather + skip + relu (bf16 hr), 4-deep MLP ----------------
__global__ __launch_bounds__(256) void gather_kernel(
    const bf16_t* __restrict__ hr, const int2* __restrict__ edgebuf,
    const int* __restrict__ offs, const int* __restrict__ deg,
    const float* __restrict__ skip, float* __restrict__ out,
    int n_nodes) {
  const long gid = (long)blockIdx.x * 256 + threadIdx.x;
  const int n = (int)(gid >> 4);
  if (n >= n_nodes) return;
  const int c = (int)(gid & 15) * 4;

  const int beg = offs[n];
  const int cnt = deg[n];

  float4 acc0 = {0.f, 0.f, 0.f, 0.f};
  float4 acc1 = {0.f, 0.f, 0.f, 0.f};
  int i = 0;
  for (; i + 3 < cnt; i += 4) {
    const int2 e0 = edgebuf[beg + i];
    const int2 e1 = edgebuf[beg + i + 1];
    const int2 e2 = edgebuf[beg + i + 2];
    const int2 e3 = edgebuf[beg + i + 3];
    const uint2 v0 = *reinterpret_cast<const uint2*>(
        &hr[((long)(((unsigned)e0.x) >> 27) * n_nodes + (e0.x & SRC_MASK)) * 64 + c]);
    const uint2 v1 = *reinterpret_cast<const uint2*>(
        &hr[((long)(((unsigned)e1.x) >> 27) * n_nodes + (e1.x & SRC_MASK)) * 64 + c]);
    const uint2 v2 = *reinterpret_cast<const uint2*>(
        &hr[((long)(((unsigned)e2.x) >> 27) * n_nodes + (e2.x & SRC_MASK)) * 64 + c]);
    const uint2 v3 = *reinterpret_cast<const uint2*>(
        &hr[((long)(((unsigned)e3.x) >> 27) * n_nodes + (e3.x & SRC_MASK)) * 64 + c]);
    const float n0 = __int_as_float(e0.y), n1 = __int_as_float(e1.y);
    const float n2 = __int_as_float(e2.y), n3 = __int_as_float(e3.y);
    acc0.x += bf2f(v0.x & 0xffff) * n0; acc0.y += bf2f(v0.x >> 16) * n0;
    acc0.z += bf2f(v0.y & 0xffff) * n0; acc0.w += bf2f(v0.y >> 16) * n0;
    acc1.x += bf2f(v1.x & 0xffff) * n1; acc1.y += bf2f(v1.x >> 16) * n1;
    acc1.z += bf2f(v1.y & 0xffff) * n1; acc1.w += bf2f(v1.y >> 16) * n1;
    acc0.x += bf2f(v2.x & 0xffff) * n2; acc0.y += bf2f(v2.x >> 16) * n2;
    acc0.z += bf2f(v2.y & 0xffff) * n2; acc0.w += bf2f(v2.y >> 16) * n2;
    acc1.x += bf2f(v3.x & 0xffff) * n3; acc1.y += bf2f(v3.x >> 16) * n3;
    acc1.z += bf2f(v3.y & 0xffff) * n3; acc1.w += bf2f(v3.y >> 16) * n3;
  }
  for (; i < cnt; ++i) {
    const int2 ea = edgebuf[beg + i];
    const float na = __int_as_float(ea.y);
    const uint2 va = *reinterpret_cast<const uint2*>(
        &hr[((long)(((unsigned)ea.x) >> 27) * n_nodes + (ea.x & SRC_MASK)) * 64 + c]);
    acc0.x += bf2f(va.x & 0xffff) * na; acc0.y += bf2f(va.x >> 16) * na;
    acc0.z += bf2f(va.y & 0xffff) * na; acc0.w += bf2f(va.y >> 16) * na;
  }
  float4 a;
  a.x = acc0.x + acc1.x; a.y = acc0.y + acc1.y;
  a.z = acc0.z + acc1.z; a.w = acc0.w + acc1.w;
  if (skip != nullptr) {
    const float4 s = *reinterpret_cast<const float4*>(&skip[(long)n * 64 + c]);
    a.x += s.x; a.y += s.y; a.z += s.z; a.w += s.w;
  }
  a.x = fmaxf(a.x, 0.f); a.y = fmaxf(a.y, 0.f);
  a.z = fmaxf(a.z, 0.f); a.w = fmaxf(a.w, 0.f);
  *reinterpret_cast<float4*>(&out[(long)n * 64 + c]) = a;
}

// ---------------- heads ----------------
// Weight tile stored TRANSPOSED in LDS: wlt[k][s]. At fixed k the wave's 23
// distinct s-values span 23 consecutive words -> conflict-free (was ~23-way
// conflict on wl[s][k] stride-64: 2.53e7 SQ_LDS_BANK_CONFLICT in R6).
__global__ __launch_bounds__(256) void heads_kernel(
    const float* __restrict__ x, const float* __restrict__ Wa,
    const float* __restrict__ ba, const float* __restrict__ Wb,
    const float* __restrict__ bb, float* __restrict__ out, int n_nodes) {
  __shared__ float xs[64][65];
  __shared__ float wlt[64][24];  // [k][s], padded to 24
  __shared__ float bl[23];
  const int tid = threadIdx.x;
  const int base = blockIdx.x * 64;

  for (int idx = tid; idx < 2 * 64; idx += 256)
    wlt[idx & 63][idx >> 6] = Wa[idx];
  for (int idx = tid; idx < 21 * 64; idx += 256)
    wlt[idx & 63][2 + (idx >> 6)] = Wb[idx];
  if (tid < 2) bl[tid] = ba[tid];
  else if (tid < 23) bl[tid] = bb[tid - 2];
  const int nrows = min(64, n_nodes - base);
  for (int idx = tid; idx < nrows * 64; idx += 256)
    xs[idx >> 6][idx & 63] = x[(long)base * 64 + idx];
  __syncthreads();

  for (int idx = tid; idx < nrows * 23; idx += 256) {
    const int n = idx / 23;
    const int s = idx % 23;
    float acc = 0.f;
#pragma unroll
    for (int k = 0; k < 64; ++k) acc += xs[n][k] * wlt[k][s];
    acc += bl[s];
    const long node = base + n;
    if (s < 2) out[node * 2 + s] = acc;
    else out[(long)n_nodes * 2 + node * 21 + (s - 2)] = acc;
  }
}

static inline char* align_up(char* p, size_t a) {
  return (char*)(((uintptr_t)p + a - 1) & ~(uintptr_t)(a - 1));
}

extern "C" void kernel_launch(void* const* d_in, const int* in_sizes, int n_in,
                              void* d_out, int out_size, void* d_ws, size_t ws_size,
                              hipStream_t stream) {
  const float* v    = (const float*)d_in[0];
  const int*   esrc = (const int*)d_in[1];
  const int*   edst = (const int*)d_in[2];
  const int*   erel = (const int*)d_in[3];
  const float* norm = (const float*)d_in[4];
  const float* W1   = (const float*)d_in[5];
  const float* W2   = (const float*)d_in[6];
  const float* W3   = (const float*)d_in[7];
  const float* Wa   = (const float*)d_in[8];
  const float* ba   = (const float*)d_in[9];
  const float* Wb   = (const float*)d_in[10];
  const float* bb   = (const float*)d_in[11];

  const int nN = in_sizes[0] / D;  // 100000
  const int E  = in_sizes[1];      // 1200000
  const int nb = (nN + 255) >> 8;  // 256-node buckets

  // ---- workspace layout
  char* p = (char*)d_ws;
  bf16_t* hr = (bf16_t*)p;            p += 3L * nN * D * sizeof(bf16_t);
  p = align_up(p, 16);
  float* bufA = (float*)p;            p += (long)nN * D * sizeof(float);
  float* bufB = (float*)p;            p += (long)nN * D * sizeof(float);
  int* deg      = (int*)p;            p += (long)nN * sizeof(int);
  int* offs     = (int*)p;            p += (long)nN * sizeof(int);
  int* bcur     = (int*)p;            p += (long)nb * sizeof(int);
  int* partials = (int*)p;            p += 256 * sizeof(int);
  p = align_up(p, 16);
  int2* edgebuf = (int2*)p;           p += (long)E * sizeof(int2);
  int2* binpay  = (int2*)p;           p += (long)E * sizeof(int2);
  unsigned char* bindst = (unsigned char*)p;  p += (long)E;

  const int eblocks = (E + 255) / 256;
  const int tblocks = (nN + 63) / 64;
  const int gblocks = (int)(((long)nN * 16 + 255) / 256);
  const int nchunks = (nN + 1023) / 1024;
  const int ablocks = (E + ABLK - 1) / ABLK;

  // ---- CSR build (once per call)
  hipMemsetAsync(deg, 0, (size_t)nN * sizeof(int), stream);
  hipMemsetAsync(bcur, 0, (size_t)nb * sizeof(int), stream);
  hist_kernel<<<eblocks, 256, 0, stream>>>(edst, deg, E);
  scan1_kernel<<<nchunks, 256, 0, stream>>>(deg, offs, partials, nN);
  scan2_kernel<<<1, 256, 0, stream>>>(partials, nchunks);
  scan3_kernel<<<(nN + 255) / 256, 256, 0, stream>>>(offs, partials, nN);
  binA_kernel<<<ablocks, ATHR, 0, stream>>>(esrc, edst, erel, norm, offs, bcur,
                                            binpay, bindst, E, nb);
  binB_kernel<<<nb, 256, 0, stream>>>(binpay, bindst, offs, edgebuf, nN, E);

  // ---- layer 1: v -> bufA (no skip)
  transform_kernel<<<tblocks, 192, 0, stream>>>(v, W1, hr, nN);
  gather_kernel<<<gblocks, 256, 0, stream>>>(hr, edgebuf, offs, deg, nullptr, bufA, nN);

  // ---- layer 2: bufA -> bufB (skip)
  transform_kernel<<<tblocks, 192, 0, stream>>>(bufA, W2, hr, nN);
  gather_kernel<<<gblocks, 256, 0, stream>>>(hr, edgebuf, offs, deg, bufA, bufB, nN);

  // ---- layer 3: bufB -> bufA (skip)
  transform_kernel<<<tblocks, 192, 0, stream>>>(bufB, W3, hr, nN);
  gather_kernel<<<gblocks, 256, 0, stream>>>(hr, edgebuf, offs, deg, bufB, bufA, nN);

  // ---- heads
  heads_kernel<<<tblocks, 256, 0, stream>>>(bufA, Wa, ba, Wb, bb, (float*)d_out, nN);
}

// Round 10
// 388.862 us; speedup vs baseline: 1.7566x; 1.0080x over previous
//
#include <hip/hip_runtime.h>

#define D 64
#define NREL 3
#define SRC_MASK 0x07FFFFFF
#define ATHR 512
#define APT 8
#define ABLK (ATHR * APT)  // 4096 edges per binA block

#define XS_STRIDE 66   // float2-aligned; 8-row spacing = 528 % 32 = 16 -> conflict-free
#define WL_STRIDE 36   // uint4-aligned bf16-pair row; od-span covers 32 banks once per r

typedef unsigned short bf16_t;

__device__ __forceinline__ float bf2f(unsigned int u16) {
  return __uint_as_float(u16 << 16);
}
__device__ __forceinline__ unsigned int f2bf(float f) {
  unsigned int x = __float_as_uint(f);
  return (x + 0x7fffu + ((x >> 16) & 1u)) >> 16;  // round-to-nearest-even
}

// ---------------- transform: hr[r][n][od] = sum_k x[n][k]*W[r][k][od] (bf16 out) ----
// LDS: xs f32 [64][66] = 16.9 KB, W as bf16-pairs [3][64][36] = 27.6 KB -> 44.5 KB
// -> 3 blocks/CU (was 65 KB -> 2 blocks/CU, 12.7% occupancy in R9).
__global__ __launch_bounds__(192) void transform_kernel(
    const float* __restrict__ x, const float* __restrict__ W,
    bf16_t* __restrict__ hr, int n_nodes) {
  __shared__ float xs[64 * XS_STRIDE];
  __shared__ unsigned int wlu[NREL * 64 * WL_STRIDE];
  const int tid = threadIdx.x;
  const int base = blockIdx.x * 64;
  const int nrows = min(64, n_nodes - base);

  // stage W: 3*64*32 = 6144 bf16-pairs
  for (int idx = tid; idx < 6144; idx += 192) {
    const int rk = idx >> 5;   // r*64 + k
    const int c2 = idx & 31;   // pair index
    const float2 w2 = *reinterpret_cast<const float2*>(&W[rk * 64 + c2 * 2]);
    wlu[rk * WL_STRIDE + c2] = f2bf(w2.x) | (f2bf(w2.y) << 16);
  }
  // stage x as float2 (stride 66 keeps float2 alignment)
  for (int idx = tid; idx < 64 * 32; idx += 192) {
    const int n = idx >> 5;
    const int c = (idx & 31) * 2;
    float2 v = {0.f, 0.f};
    if (n < nrows) v = *reinterpret_cast<const float2*>(&x[(long)(base + n) * 64 + c]);
    *reinterpret_cast<float2*>(&xs[n * XS_STRIDE + c]) = v;
  }
  __syncthreads();

  const int jt = tid % 24;  // j0 = jt*8 in [0,192): never crosses a relation boundary
  const int nt = tid / 24;  // 8 n-tiles of 8 nodes
  const int j0 = jt * 8;
  const int r = j0 >> 6;
  const int od0 = j0 & 63;
  const int n0 = nt * 8;
  const unsigned int* wrow = &wlu[r * (64 * WL_STRIDE)];

  float acc[8][8];
#pragma unroll
  for (int i = 0; i < 8; ++i)
#pragma unroll
    for (int j = 0; j < 8; ++j) acc[i][j] = 0.f;

#pragma unroll 2
  for (int k = 0; k < 64; ++k) {
    float a[8];
#pragma unroll
    for (int i = 0; i < 8; ++i) a[i] = xs[(n0 + i) * XS_STRIDE + k];
    const uint4 bp = *reinterpret_cast<const uint4*>(&wrow[k * WL_STRIDE + (od0 >> 1)]);
    float bbv[8];
    bbv[0] = __uint_as_float(bp.x << 16);
    bbv[1] = __uint_as_float(bp.x & 0xffff0000u);
    bbv[2] = __uint_as_float(bp.y << 16);
    bbv[3] = __uint_as_float(bp.y & 0xffff0000u);
    bbv[4] = __uint_as_float(bp.z << 16);
    bbv[5] = __uint_as_float(bp.z & 0xffff0000u);
    bbv[6] = __uint_as_float(bp.w << 16);
    bbv[7] = __uint_as_float(bp.w & 0xffff0000u);
#pragma unroll
    for (int i = 0; i < 8; ++i)
#pragma unroll
      for (int j = 0; j < 8; ++j) acc[i][j] += a[i] * bbv[j];
  }

#pragma unroll
  for (int i = 0; i < 8; ++i) {
    const int n = n0 + i;
    if (n < nrows) {
      uint4 o;
      o.x = f2bf(acc[i][0]) | (f2bf(acc[i][1]) << 16);
      o.y = f2bf(acc[i][2]) | (f2bf(acc[i][3]) << 16);
      o.z = f2bf(acc[i][4]) | (f2bf(acc[i][5]) << 16);
      o.w = f2bf(acc[i][6]) | (f2bf(acc[i][7]) << 16);
      *reinterpret_cast<uint4*>(
          &hr[((long)r * n_nodes + base + n) * 64 + od0]) = o;
    }
  }
}

// ---------------- CSR build ----------------
__global__ __launch_bounds__(256) void hist_kernel(
    const int* __restrict__ dst, int* __restrict__ deg, int n_edges) {
  const int e = blockIdx.x * 256 + threadIdx.x;
  if (e < n_edges) atomicAdd(&deg[dst[e]], 1);
}

__global__ __launch_bounds__(256) void scan1_kernel(
    const int* __restrict__ deg, int* __restrict__ offs,
    int* __restrict__ partials, int n_nodes) {
  __shared__ int ssum[256];
  const int t = threadIdx.x;
  const int base = blockIdx.x * 1024 + t * 4;
  int v0 = (base + 0 < n_nodes) ? deg[base + 0] : 0;
  int v1 = (base + 1 < n_nodes) ? deg[base + 1] : 0;
  int v2 = (base + 2 < n_nodes) ? deg[base + 2] : 0;
  int v3 = (base + 3 < n_nodes) ? deg[base + 3] : 0;
  const int lsum = v0 + v1 + v2 + v3;
  ssum[t] = lsum;
  __syncthreads();
  for (int off = 1; off < 256; off <<= 1) {
    const int add = (t >= off) ? ssum[t - off] : 0;
    __syncthreads();
    ssum[t] += add;
    __syncthreads();
  }
  const int excl = ssum[t] - lsum;
  if (base + 0 < n_nodes) offs[base + 0] = excl;
  if (base + 1 < n_nodes) offs[base + 1] = excl + v0;
  if (base + 2 < n_nodes) offs[base + 2] = excl + v0 + v1;
  if (base + 3 < n_nodes) offs[base + 3] = excl + v0 + v1 + v2;
  if (t == 255) partials[blockIdx.x] = ssum[255];
}

__global__ __launch_bounds__(256) void scan2_kernel(int* __restrict__ partials,
                                                    int n_chunks) {
  __shared__ int s[256];
  const int t = threadIdx.x;
  const int v = (t < n_chunks) ? partials[t] : 0;
  s[t] = v;
  __syncthreads();
  for (int off = 1; off < 256; off <<= 1) {
    const int add = (t >= off) ? s[t - off] : 0;
    __syncthreads();
    s[t] += add;
    __syncthreads();
  }
  if (t < n_chunks) partials[t] = s[t] - v;
}

__global__ __launch_bounds__(256) void scan3_kernel(
    int* __restrict__ offs, const int* __restrict__ partials, int n_nodes) {
  const int i = blockIdx.x * 256 + threadIdx.x;
  if (i < n_nodes) offs[i] += partials[i >> 10];
}

// Phase A: bin edges by dst>>8 into the bucket's final CSR range (unordered within
// bucket). Per-block LDS counting -> ONE global reserve atomic per (block,bucket).
__global__ __launch_bounds__(ATHR) void binA_kernel(
    const int* __restrict__ src, const int* __restrict__ dst,
    const int* __restrict__ rel, const float* __restrict__ norm,
    const int* __restrict__ offs, int* __restrict__ bcur,
    int2* __restrict__ binpay, unsigned char* __restrict__ bindst,
    int n_edges, int nb) {
  __shared__ int cnt[400];
  __shared__ int basea[400];
  const int t = threadIdx.x;
  const long e0 = (long)blockIdx.x * ABLK;

  for (int b = t; b < nb; b += ATHR) cnt[b] = 0;
  __syncthreads();

  int2 pay[APT];
  int bk[APT], slot[APT], dlo[APT];
#pragma unroll
  for (int i = 0; i < APT; ++i) {
    const long e = e0 + t + (long)i * ATHR;
    if (e < n_edges) {
      const int d = dst[e];
      bk[i] = d >> 8;
      dlo[i] = d & 255;
      pay[i] = make_int2(src[e] | (rel[e] << 27), __float_as_int(norm[e]));
      slot[i] = atomicAdd(&cnt[bk[i]], 1);
    } else {
      bk[i] = -1;
    }
  }
  __syncthreads();

  for (int b = t; b < nb; b += ATHR) {
    const int c = cnt[b];
    basea[b] = c ? (offs[b << 8] + atomicAdd(&bcur[b], c)) : 0;
  }
  __syncthreads();

#pragma unroll
  for (int i = 0; i < APT; ++i) {
    if (bk[i] >= 0) {
      const int pos = basea[bk[i]] + slot[i];
      binpay[pos] = pay[i];
      bindst[pos] = (unsigned char)dlo[i];
    }
  }
}

// Phase B: one block per bucket; scatter within the bucket's L2-resident CSR
// region to exact per-node position using LDS cursors (no global atomics).
__global__ __launch_bounds__(256) void binB_kernel(
    const int2* __restrict__ binpay, const unsigned char* __restrict__ bindst,
    const int* __restrict__ offs, int2* __restrict__ edgebuf,
    int n_nodes, int n_edges) {
  __shared__ int lcnt[256];
  const int b = blockIdx.x;
  const int t = threadIdx.x;
  lcnt[t] = 0;
  __syncthreads();
  const int start = offs[b << 8];
  const int nbase = (b + 1) << 8;
  const int end = (nbase >= n_nodes) ? n_edges : offs[nbase];
  for (int i = start + t; i < end; i += 256) {
    const int2 pay = binpay[i];
    const int dl = bindst[i];
    const int pos = offs[(b << 8) + dl] + atomicAdd(&lcnt[dl], 1);
    edgebuf[pos] = pay;
  }
}

// ---------------- fused gather + skip + relu (bf16 hr), 4-deep MLP ----------------
__global__ __launch_bounds__(256) void gather_kernel(
    const bf16_t* __restrict__ hr, const int2* __restrict__ edgebuf,
    const int* __restrict__ offs, const int* __restrict__ deg,
    const float* __restrict__ skip, float* __restrict__ out,
    int n_nodes) {
  const long gid = (long)blockIdx.x * 256 + threadIdx.x;
  const int n = (int)(gid >> 4);
  if (n >= n_nodes) return;
  const int c = (int)(gid & 15) * 4;

  const int beg = offs[n];
  const int cnt = deg[n];

  float4 acc0 = {0.f, 0.f, 0.f, 0.f};
  float4 acc1 = {0.f, 0.f, 0.f, 0.f};
  int i = 0;
  for (; i + 3 < cnt; i += 4) {
    const int2 e0 = edgebuf[beg + i];
    const int2 e1 = edgebuf[beg + i + 1];
    const int2 e2 = edgebuf[beg + i + 2];
    const int2 e3 = edgebuf[beg + i + 3];
    const uint2 v0 = *reinterpret_cast<const uint2*>(
        &hr[((long)(((unsigned)e0.x) >> 27) * n_nodes + (e0.x & SRC_MASK)) * 64 + c]);
    const uint2 v1 = *reinterpret_cast<const uint2*>(
        &hr[((long)(((unsigned)e1.x) >> 27) * n_nodes + (e1.x & SRC_MASK)) * 64 + c]);
    const uint2 v2 = *reinterpret_cast<const uint2*>(
        &hr[((long)(((unsigned)e2.x) >> 27) * n_nodes + (e2.x & SRC_MASK)) * 64 + c]);
    const uint2 v3 = *reinterpret_cast<const uint2*>(
        &hr[((long)(((unsigned)e3.x) >> 27) * n_nodes + (e3.x & SRC_MASK)) * 64 + c]);
    const float n0 = __int_as_float(e0.y), n1 = __int_as_float(e1.y);
    const float n2 = __int_as_float(e2.y), n3 = __int_as_float(e3.y);
    acc0.x += bf2f(v0.x & 0xffff) * n0; acc0.y += bf2f(v0.x >> 16) * n0;
    acc0.z += bf2f(v0.y & 0xffff) * n0; acc0.w += bf2f(v0.y >> 16) * n0;
    acc1.x += bf2f(v1.x & 0xffff) * n1; acc1.y += bf2f(v1.x >> 16) * n1;
    acc1.z += bf2f(v1.y & 0xffff) * n1; acc1.w += bf2f(v1.y >> 16) * n1;
    acc0.x += bf2f(v2.x & 0xffff) * n2; acc0.y += bf2f(v2.x >> 16) * n2;
    acc0.z += bf2f(v2.y & 0xffff) * n2; acc0.w += bf2f(v2.y >> 16) * n2;
    acc1.x += bf2f(v3.x & 0xffff) * n3; acc1.y += bf2f(v3.x >> 16) * n3;
    acc1.z += bf2f(v3.y & 0xffff) * n3; acc1.w += bf2f(v3.y >> 16) * n3;
  }
  for (; i < cnt; ++i) {
    const int2 ea = edgebuf[beg + i];
    const float na = __int_as_float(ea.y);
    const uint2 va = *reinterpret_cast<const uint2*>(
        &hr[((long)(((unsigned)ea.x) >> 27) * n_nodes + (ea.x & SRC_MASK)) * 64 + c]);
    acc0.x += bf2f(va.x & 0xffff) * na; acc0.y += bf2f(va.x >> 16) * na;
    acc0.z += bf2f(va.y & 0xffff) * na; acc0.w += bf2f(va.y >> 16) * na;
  }
  float4 a;
  a.x = acc0.x + acc1.x; a.y = acc0.y + acc1.y;
  a.z = acc0.z + acc1.z; a.w = acc0.w + acc1.w;
  if (skip != nullptr) {
    const float4 s = *reinterpret_cast<const float4*>(&skip[(long)n * 64 + c]);
    a.x += s.x; a.y += s.y; a.z += s.z; a.w += s.w;
  }
  a.x = fmaxf(a.x, 0.f); a.y = fmaxf(a.y, 0.f);
  a.z = fmaxf(a.z, 0.f); a.w = fmaxf(a.w, 0.f);
  *reinterpret_cast<float4*>(&out[(long)n * 64 + c]) = a;
}

// ---------------- heads ----------------
// Weight tile TRANSPOSED in LDS (wlt[k][s]) -> conflict-free (R9-verified:
// heads dropped out of top-5; was 72 us / 2.53e7 conflicts).
__global__ __launch_bounds__(256) void heads_kernel(
    const float* __restrict__ x, const float* __restrict__ Wa,
    const float* __restrict__ ba, const float* __restrict__ Wb,
    const float* __restrict__ bb, float* __restrict__ out, int n_nodes) {
  __shared__ float xs[64][65];
  __shared__ float wlt[64][24];  // [k][s], padded to 24
  __shared__ float bl[23];
  const int tid = threadIdx.x;
  const int base = blockIdx.x * 64;

  for (int idx = tid; idx < 2 * 64; idx += 256)
    wlt[idx & 63][idx >> 6] = Wa[idx];
  for (int idx = tid; idx < 21 * 64; idx += 256)
    wlt[idx & 63][2 + (idx >> 6)] = Wb[idx];
  if (tid < 2) bl[tid] = ba[tid];
  else if (tid < 23) bl[tid] = bb[tid - 2];
  const int nrows = min(64, n_nodes - base);
  for (int idx = tid; idx < nrows * 64; idx += 256)
    xs[idx >> 6][idx & 63] = x[(long)base * 64 + idx];
  __syncthreads();

  for (int idx = tid; idx < nrows * 23; idx += 256) {
    const int n = idx / 23;
    const int s = idx % 23;
    float acc = 0.f;
#pragma unroll
    for (int k = 0; k < 64; ++k) acc += xs[n][k] * wlt[k][s];
    acc += bl[s];
    const long node = base + n;
    if (s < 2) out[node * 2 + s] = acc;
    else out[(long)n_nodes * 2 + node * 21 + (s - 2)] = acc;
  }
}

static inline char* align_up(char* p, size_t a) {
  return (char*)(((uintptr_t)p + a - 1) & ~(uintptr_t)(a - 1));
}

extern "C" void kernel_launch(void* const* d_in, const int* in_sizes, int n_in,
                              void* d_out, int out_size, void* d_ws, size_t ws_size,
                              hipStream_t stream) {
  const float* v    = (const float*)d_in[0];
  const int*   esrc = (const int*)d_in[1];
  const int*   edst = (const int*)d_in[2];
  const int*   erel = (const int*)d_in[3];
  const float* norm = (const float*)d_in[4];
  const float* W1   = (const float*)d_in[5];
  const float* W2   = (const float*)d_in[6];
  const float* W3   = (const float*)d_in[7];
  const float* Wa   = (const float*)d_in[8];
  const float* ba   = (const float*)d_in[9];
  const float* Wb   = (const float*)d_in[10];
  const float* bb   = (const float*)d_in[11];

  const int nN = in_sizes[0] / D;  // 100000
  const int E  = in_sizes[1];      // 1200000
  const int nb = (nN + 255) >> 8;  // 256-node buckets

  // ---- workspace layout
  char* p = (char*)d_ws;
  bf16_t* hr = (bf16_t*)p;            p += 3L * nN * D * sizeof(bf16_t);
  p = align_up(p, 16);
  float* bufA = (float*)p;            p += (long)nN * D * sizeof(float);
  float* bufB = (float*)p;            p += (long)nN * D * sizeof(float);
  int* deg      = (int*)p;            p += (long)nN * sizeof(int);
  int* offs     = (int*)p;            p += (long)nN * sizeof(int);
  int* bcur     = (int*)p;            p += (long)nb * sizeof(int);
  int* partials = (int*)p;            p += 256 * sizeof(int);
  p = align_up(p, 16);
  int2* edgebuf = (int2*)p;           p += (long)E * sizeof(int2);
  int2* binpay  = (int2*)p;           p += (long)E * sizeof(int2);
  unsigned char* bindst = (unsigned char*)p;  p += (long)E;

  const int eblocks = (E + 255) / 256;
  const int tblocks = (nN + 63) / 64;
  const int gblocks = (int)(((long)nN * 16 + 255) / 256);
  const int nchunks = (nN + 1023) / 1024;
  const int ablocks = (E + ABLK - 1) / ABLK;

  // ---- CSR build (once per call)
  hipMemsetAsync(deg, 0, (size_t)nN * sizeof(int), stream);
  hipMemsetAsync(bcur, 0, (size_t)nb * sizeof(int), stream);
  hist_kernel<<<eblocks, 256, 0, stream>>>(edst, deg, E);
  scan1_kernel<<<nchunks, 256, 0, stream>>>(deg, offs, partials, nN);
  scan2_kernel<<<1, 256, 0, stream>>>(partials, nchunks);
  scan3_kernel<<<(nN + 255) / 256, 256, 0, stream>>>(offs, partials, nN);
  binA_kernel<<<ablocks, ATHR, 0, stream>>>(esrc, edst, erel, norm, offs, bcur,
                                            binpay, bindst, E, nb);
  binB_kernel<<<nb, 256, 0, stream>>>(binpay, bindst, offs, edgebuf, nN, E);

  // ---- layer 1: v -> bufA (no skip)
  transform_kernel<<<tblocks, 192, 0, stream>>>(v, W1, hr, nN);
  gather_kernel<<<gblocks, 256, 0, stream>>>(hr, edgebuf, offs, deg, nullptr, bufA, nN);

  // ---- layer 2: bufA -> bufB (skip)
  transform_kernel<<<tblocks, 192, 0, stream>>>(bufA, W2, hr, nN);
  gather_kernel<<<gblocks, 256, 0, stream>>>(hr, edgebuf, offs, deg, bufA, bufB, nN);

  // ---- layer 3: bufB -> bufA (skip)
  transform_kernel<<<tblocks, 192, 0, stream>>>(bufB, W3, hr, nN);
  gather_kernel<<<gblocks, 256, 0, stream>>>(hr, edgebuf, offs, deg, bufB, bufA, nN);

  // ---- heads
  heads_kernel<<<tblocks, 256, 0, stream>>>(bufA, Wa, ba, Wb, bb, (float*)d_out, nN);
}

// Round 11
// 308.055 us; speedup vs baseline: 2.2174x; 1.2623x over previous
//
#include <hip/hip_runtime.h>

#define D 64
#define NREL 3
#define SRC_MASK 0x07FFFFFF
#define ATHR 512
#define APT 8
#define ABLK (ATHR * APT)  // 4096 edges per binA block

typedef unsigned short bf16_t;
typedef __attribute__((ext_vector_type(8))) short short8v;   // 8 bf16 = 4 VGPRs
typedef __attribute__((ext_vector_type(4))) float float4v;

__device__ __forceinline__ float bf2f(unsigned int u16) {
  return __uint_as_float(u16 << 16);
}
__device__ __forceinline__ unsigned int f2bf(float f) {
  unsigned int x = __float_as_uint(f);
  return (x + 0x7fffu + ((x >> 16) & 1u)) >> 16;  // round-to-nearest-even
}

// ---------------- f32 -> bf16 convert (for layer-1 input) ----------------
__global__ __launch_bounds__(256) void conv_kernel(
    const float* __restrict__ in, bf16_t* __restrict__ out, int n4) {
  const int i = blockIdx.x * 256 + threadIdx.x;
  if (i >= n4) return;
  const float4 f = reinterpret_cast<const float4*>(in)[i];
  uint2 o;
  o.x = f2bf(f.x) | (f2bf(f.y) << 16);
  o.y = f2bf(f.z) | (f2bf(f.w) << 16);
  reinterpret_cast<uint2*>(out)[i] = o;
}

// ---------------- transform via MFMA: hr[r][n][od] = sum_k xb[n][k]*W[r][k][od] ----
// Per block: 256 thr = 4 waves, 64 nodes (16/wave). W^T staged bf16 in LDS
// (wt[r][od][k], row 72 elems = 144 B, 16B-aligned frag reads). A-operand =
// W^T tile (M=od), B-operand = X^T tile (N=node). K-accumulate 2x mfma K=32.
// C/D mapping (m89-verified): col=lane&15 (node), row=(lane>>4)*4+reg (od).
// A/B frag k-convention identical for both operands -> k-permutation cancels.
__global__ __launch_bounds__(256) void transform_kernel(
    const bf16_t* __restrict__ xb, const float* __restrict__ W,
    bf16_t* __restrict__ hr, int n_nodes) {
  __shared__ bf16_t wt[NREL * 64 * 72];  // 27.6 KB
  const int tid = threadIdx.x;

  for (int idx = tid; idx < NREL * 64 * 64; idx += 256) {
    const int r = idx >> 12;
    const int k = (idx >> 6) & 63;
    const int od = idx & 63;
    wt[(r * 64 + od) * 72 + k] = (bf16_t)f2bf(W[idx]);
  }
  __syncthreads();

  const int wid = tid >> 6;
  const int lane = tid & 63;
  const int n0 = blockIdx.x * 64 + wid * 16;
  if (n0 >= n_nodes) return;  // after barrier; nN % 16 == 0 so strips are full

  // B-frags: lane holds X[n0+(lane&15)][k], k = h*32 + (lane>>4)*8 + j
  const bf16_t* xrow = &xb[(long)(n0 + (lane & 15)) * 64 + (lane >> 4) * 8];
  const short8v bx0 = *reinterpret_cast<const short8v*>(xrow);
  const short8v bx1 = *reinterpret_cast<const short8v*>(xrow + 32);

  const int node = n0 + (lane & 15);
#pragma unroll
  for (int r = 0; r < NREL; ++r) {
#pragma unroll
    for (int t = 0; t < 4; ++t) {
      const bf16_t* wrow =
          &wt[(r * 64 + t * 16 + (lane & 15)) * 72 + (lane >> 4) * 8];
      const short8v a0 = *reinterpret_cast<const short8v*>(wrow);
      const short8v a1 = *reinterpret_cast<const short8v*>(wrow + 32);
      float4v acc = {0.f, 0.f, 0.f, 0.f};
      acc = __builtin_amdgcn_mfma_f32_16x16x32_bf16(a0, bx0, acc, 0, 0, 0);
      acc = __builtin_amdgcn_mfma_f32_16x16x32_bf16(a1, bx1, acc, 0, 0, 0);
      const int od = t * 16 + (lane >> 4) * 4;
      uint2 o;
      o.x = f2bf(acc[0]) | (f2bf(acc[1]) << 16);
      o.y = f2bf(acc[2]) | (f2bf(acc[3]) << 16);
      *reinterpret_cast<uint2*>(&hr[((long)r * n_nodes + node) * 64 + od]) = o;
    }
  }
}

// ---------------- CSR build ----------------
__global__ __launch_bounds__(256) void hist_kernel(
    const int* __restrict__ dst, int* __restrict__ deg, int n_edges) {
  const int e = blockIdx.x * 256 + threadIdx.x;
  if (e < n_edges) atomicAdd(&deg[dst[e]], 1);
}

__global__ __launch_bounds__(256) void scan1_kernel(
    const int* __restrict__ deg, int* __restrict__ offs,
    int* __restrict__ partials, int n_nodes) {
  __shared__ int ssum[256];
  const int t = threadIdx.x;
  const int base = blockIdx.x * 1024 + t * 4;
  int v0 = (base + 0 < n_nodes) ? deg[base + 0] : 0;
  int v1 = (base + 1 < n_nodes) ? deg[base + 1] : 0;
  int v2 = (base + 2 < n_nodes) ? deg[base + 2] : 0;
  int v3 = (base + 3 < n_nodes) ? deg[base + 3] : 0;
  const int lsum = v0 + v1 + v2 + v3;
  ssum[t] = lsum;
  __syncthreads();
  for (int off = 1; off < 256; off <<= 1) {
    const int add = (t >= off) ? ssum[t - off] : 0;
    __syncthreads();
    ssum[t] += add;
    __syncthreads();
  }
  const int excl = ssum[t] - lsum;
  if (base + 0 < n_nodes) offs[base + 0] = excl;
  if (base + 1 < n_nodes) offs[base + 1] = excl + v0;
  if (base + 2 < n_nodes) offs[base + 2] = excl + v0 + v1;
  if (base + 3 < n_nodes) offs[base + 3] = excl + v0 + v1 + v2;
  if (t == 255) partials[blockIdx.x] = ssum[255];
}

__global__ __launch_bounds__(256) void scan2_kernel(int* __restrict__ partials,
                                                    int n_chunks) {
  __shared__ int s[256];
  const int t = threadIdx.x;
  const int v = (t < n_chunks) ? partials[t] : 0;
  s[t] = v;
  __syncthreads();
  for (int off = 1; off < 256; off <<= 1) {
    const int add = (t >= off) ? s[t - off] : 0;
    __syncthreads();
    s[t] += add;
    __syncthreads();
  }
  if (t < n_chunks) partials[t] = s[t] - v;
}

__global__ __launch_bounds__(256) void scan3_kernel(
    int* __restrict__ offs, const int* __restrict__ partials, int n_nodes) {
  const int i = blockIdx.x * 256 + threadIdx.x;
  if (i < n_nodes) offs[i] += partials[i >> 10];
}

// Phase A: bin edges by dst>>8 into the bucket's final CSR range (unordered within
// bucket). Per-block LDS counting -> ONE global reserve atomic per (block,bucket).
__global__ __launch_bounds__(ATHR) void binA_kernel(
    const int* __restrict__ src, const int* __restrict__ dst,
    const int* __restrict__ rel, const float* __restrict__ norm,
    const int* __restrict__ offs, int* __restrict__ bcur,
    int2* __restrict__ binpay, unsigned char* __restrict__ bindst,
    int n_edges, int nb) {
  __shared__ int cnt[400];
  __shared__ int basea[400];
  const int t = threadIdx.x;
  const long e0 = (long)blockIdx.x * ABLK;

  for (int b = t; b < nb; b += ATHR) cnt[b] = 0;
  __syncthreads();

  int2 pay[APT];
  int bk[APT], slot[APT], dlo[APT];
#pragma unroll
  for (int i = 0; i < APT; ++i) {
    const long e = e0 + t + (long)i * ATHR;
    if (e < n_edges) {
      const int d = dst[e];
      bk[i] = d >> 8;
      dlo[i] = d & 255;
      pay[i] = make_int2(src[e] | (rel[e] << 27), __float_as_int(norm[e]));
      slot[i] = atomicAdd(&cnt[bk[i]], 1);
    } else {
      bk[i] = -1;
    }
  }
  __syncthreads();

  for (int b = t; b < nb; b += ATHR) {
    const int c = cnt[b];
    basea[b] = c ? (offs[b << 8] + atomicAdd(&bcur[b], c)) : 0;
  }
  __syncthreads();

#pragma unroll
  for (int i = 0; i < APT; ++i) {
    if (bk[i] >= 0) {
      const int pos = basea[bk[i]] + slot[i];
      binpay[pos] = pay[i];
      bindst[pos] = (unsigned char)dlo[i];
    }
  }
}

// Phase B: one block per bucket; scatter within the bucket's L2-resident CSR
// region to exact per-node position using LDS cursors (no global atomics).
__global__ __launch_bounds__(256) void binB_kernel(
    const int2* __restrict__ binpay, const unsigned char* __restrict__ bindst,
    const int* __restrict__ offs, int2* __restrict__ edgebuf,
    int n_nodes, int n_edges) {
  __shared__ int lcnt[256];
  const int b = blockIdx.x;
  const int t = threadIdx.x;
  lcnt[t] = 0;
  __syncthreads();
  const int start = offs[b << 8];
  const int nbase = (b + 1) << 8;
  const int end = (nbase >= n_nodes) ? n_edges : offs[nbase];
  for (int i = start + t; i < end; i += 256) {
    const int2 pay = binpay[i];
    const int dl = bindst[i];
    const int pos = offs[(b << 8) + dl] + atomicAdd(&lcnt[dl], 1);
    edgebuf[pos] = pay;
  }
}

// ---------------- fused gather + skip + relu (bf16 hr), 4-deep MLP ----------------
// Also emits bf16 copy of the output (xbout) to feed the next layer's MFMA.
__global__ __launch_bounds__(256) void gather_kernel(
    const bf16_t* __restrict__ hr, const int2* __restrict__ edgebuf,
    const int* __restrict__ offs, const int* __restrict__ deg,
    const float* __restrict__ skip, float* __restrict__ out,
    bf16_t* __restrict__ xbout, int n_nodes) {
  const long gid = (long)blockIdx.x * 256 + threadIdx.x;
  const int n = (int)(gid >> 4);
  if (n >= n_nodes) return;
  const int c = (int)(gid & 15) * 4;

  const int beg = offs[n];
  const int cnt = deg[n];

  float4 acc0 = {0.f, 0.f, 0.f, 0.f};
  float4 acc1 = {0.f, 0.f, 0.f, 0.f};
  int i = 0;
  for (; i + 3 < cnt; i += 4) {
    const int2 e0 = edgebuf[beg + i];
    const int2 e1 = edgebuf[beg + i + 1];
    const int2 e2 = edgebuf[beg + i + 2];
    const int2 e3 = edgebuf[beg + i + 3];
    const uint2 v0 = *reinterpret_cast<const uint2*>(
        &hr[((long)(((unsigned)e0.x) >> 27) * n_nodes + (e0.x & SRC_MASK)) * 64 + c]);
    const uint2 v1 = *reinterpret_cast<const uint2*>(
        &hr[((long)(((unsigned)e1.x) >> 27) * n_nodes + (e1.x & SRC_MASK)) * 64 + c]);
    const uint2 v2 = *reinterpret_cast<const uint2*>(
        &hr[((long)(((unsigned)e2.x) >> 27) * n_nodes + (e2.x & SRC_MASK)) * 64 + c]);
    const uint2 v3 = *reinterpret_cast<const uint2*>(
        &hr[((long)(((unsigned)e3.x) >> 27) * n_nodes + (e3.x & SRC_MASK)) * 64 + c]);
    const float n0 = __int_as_float(e0.y), n1 = __int_as_float(e1.y);
    const float n2 = __int_as_float(e2.y), n3 = __int_as_float(e3.y);
    acc0.x += bf2f(v0.x & 0xffff) * n0; acc0.y += bf2f(v0.x >> 16) * n0;
    acc0.z += bf2f(v0.y & 0xffff) * n0; acc0.w += bf2f(v0.y >> 16) * n0;
    acc1.x += bf2f(v1.x & 0xffff) * n1; acc1.y += bf2f(v1.x >> 16) * n1;
    acc1.z += bf2f(v1.y & 0xffff) * n1; acc1.w += bf2f(v1.y >> 16) * n1;
    acc0.x += bf2f(v2.x & 0xffff) * n2; acc0.y += bf2f(v2.x >> 16) * n2;
    acc0.z += bf2f(v2.y & 0xffff) * n2; acc0.w += bf2f(v2.y >> 16) * n2;
    acc1.x += bf2f(v3.x & 0xffff) * n3; acc1.y += bf2f(v3.x >> 16) * n3;
    acc1.z += bf2f(v3.y & 0xffff) * n3; acc1.w += bf2f(v3.y >> 16) * n3;
  }
  for (; i < cnt; ++i) {
    const int2 ea = edgebuf[beg + i];
    const float na = __int_as_float(ea.y);
    const uint2 va = *reinterpret_cast<const uint2*>(
        &hr[((long)(((unsigned)ea.x) >> 27) * n_nodes + (ea.x & SRC_MASK)) * 64 + c]);
    acc0.x += bf2f(va.x & 0xffff) * na; acc0.y += bf2f(va.x >> 16) * na;
    acc0.z += bf2f(va.y & 0xffff) * na; acc0.w += bf2f(va.y >> 16) * na;
  }
  float4 a;
  a.x = acc0.x + acc1.x; a.y = acc0.y + acc1.y;
  a.z = acc0.z + acc1.z; a.w = acc0.w + acc1.w;
  if (skip != nullptr) {
    const float4 s = *reinterpret_cast<const float4*>(&skip[(long)n * 64 + c]);
    a.x += s.x; a.y += s.y; a.z += s.z; a.w += s.w;
  }
  a.x = fmaxf(a.x, 0.f); a.y = fmaxf(a.y, 0.f);
  a.z = fmaxf(a.z, 0.f); a.w = fmaxf(a.w, 0.f);
  *reinterpret_cast<float4*>(&out[(long)n * 64 + c]) = a;
  if (xbout != nullptr) {
    uint2 o;
    o.x = f2bf(a.x) | (f2bf(a.y) << 16);
    o.y = f2bf(a.z) | (f2bf(a.w) << 16);
    *reinterpret_cast<uint2*>(&xbout[(long)n * 64 + c]) = o;
  }
}

// ---------------- heads ----------------
// Weight tile TRANSPOSED in LDS (wlt[k][s]) -> conflict-free (R9-verified).
__global__ __launch_bounds__(256) void heads_kernel(
    const float* __restrict__ x, const float* __restrict__ Wa,
    const float* __restrict__ ba, const float* __restrict__ Wb,
    const float* __restrict__ bb, float* __restrict__ out, int n_nodes) {
  __shared__ float xs[64][65];
  __shared__ float wlt[64][24];  // [k][s], padded to 24
  __shared__ float bl[23];
  const int tid = threadIdx.x;
  const int base = blockIdx.x * 64;

  for (int idx = tid; idx < 2 * 64; idx += 256)
    wlt[idx & 63][idx >> 6] = Wa[idx];
  for (int idx = tid; idx < 21 * 64; idx += 256)
    wlt[idx & 63][2 + (idx >> 6)] = Wb[idx];
  if (tid < 2) bl[tid] = ba[tid];
  else if (tid < 23) bl[tid] = bb[tid - 2];
  const int nrows = min(64, n_nodes - base);
  for (int idx = tid; idx < nrows * 64; idx += 256)
    xs[idx >> 6][idx & 63] = x[(long)base * 64 + idx];
  __syncthreads();

  for (int idx = tid; idx < nrows * 23; idx += 256) {
    const int n = idx / 23;
    const int s = idx % 23;
    float acc = 0.f;
#pragma unroll
    for (int k = 0; k < 64; ++k) acc += xs[n][k] * wlt[k][s];
    acc += bl[s];
    const long node = base + n;
    if (s < 2) out[node * 2 + s] = acc;
    else out[(long)n_nodes * 2 + node * 21 + (s - 2)] = acc;
  }
}

static inline char* align_up(char* p, size_t a) {
  return (char*)(((uintptr_t)p + a - 1) & ~(uintptr_t)(a - 1));
}

extern "C" void kernel_launch(void* const* d_in, const int* in_sizes, int n_in,
                              void* d_out, int out_size, void* d_ws, size_t ws_size,
                              hipStream_t stream) {
  const float* v    = (const float*)d_in[0];
  const int*   esrc = (const int*)d_in[1];
  const int*   edst = (const int*)d_in[2];
  const int*   erel = (const int*)d_in[3];
  const float* norm = (const float*)d_in[4];
  const float* W1   = (const float*)d_in[5];
  const float* W2   = (const float*)d_in[6];
  const float* W3   = (const float*)d_in[7];
  const float* Wa   = (const float*)d_in[8];
  const float* ba   = (const float*)d_in[9];
  const float* Wb   = (const float*)d_in[10];
  const float* bb   = (const float*)d_in[11];

  const int nN = in_sizes[0] / D;  // 100000
  const int E  = in_sizes[1];      // 1200000
  const int nb = (nN + 255) >> 8;  // 256-node buckets

  // ---- workspace layout
  char* p = (char*)d_ws;
  bf16_t* hr = (bf16_t*)p;            p += 3L * nN * D * sizeof(bf16_t);
  p = align_up(p, 16);
  bf16_t* xb = (bf16_t*)p;            p += (long)nN * D * sizeof(bf16_t);
  p = align_up(p, 16);
  float* bufA = (float*)p;            p += (long)nN * D * sizeof(float);
  float* bufB = (float*)p;            p += (long)nN * D * sizeof(float);
  int* deg      = (int*)p;            p += (long)nN * sizeof(int);
  int* offs     = (int*)p;            p += (long)nN * sizeof(int);
  int* bcur     = (int*)p;            p += (long)nb * sizeof(int);
  int* partials = (int*)p;            p += 256 * sizeof(int);
  p = align_up(p, 16);
  int2* edgebuf = (int2*)p;           p += (long)E * sizeof(int2);
  int2* binpay  = (int2*)p;           p += (long)E * sizeof(int2);
  unsigned char* bindst = (unsigned char*)p;  p += (long)E;

  const int eblocks = (E + 255) / 256;
  const int tblocks = (nN + 63) / 64;
  const int gblocks = (int)(((long)nN * 16 + 255) / 256);
  const int nchunks = (nN + 1023) / 1024;
  const int ablocks = (E + ABLK - 1) / ABLK;
  const int cblocks = (nN * D / 4 + 255) / 256;

  // ---- CSR build (once per call)
  hipMemsetAsync(deg, 0, (size_t)nN * sizeof(int), stream);
  hipMemsetAsync(bcur, 0, (size_t)nb * sizeof(int), stream);
  hist_kernel<<<eblocks, 256, 0, stream>>>(edst, deg, E);
  scan1_kernel<<<nchunks, 256, 0, stream>>>(deg, offs, partials, nN);
  scan2_kernel<<<1, 256, 0, stream>>>(partials, nchunks);
  scan3_kernel<<<(nN + 255) / 256, 256, 0, stream>>>(offs, partials, nN);
  binA_kernel<<<ablocks, ATHR, 0, stream>>>(esrc, edst, erel, norm, offs, bcur,
                                            binpay, bindst, E, nb);
  binB_kernel<<<nb, 256, 0, stream>>>(binpay, bindst, offs, edgebuf, nN, E);

  // ---- layer 1: v -> bufA (no skip); xb = bf16(v)
  conv_kernel<<<cblocks, 256, 0, stream>>>(v, xb, nN * D / 4);
  transform_kernel<<<tblocks, 256, 0, stream>>>(xb, W1, hr, nN);
  gather_kernel<<<gblocks, 256, 0, stream>>>(hr, edgebuf, offs, deg, nullptr,
                                             bufA, xb, nN);

  // ---- layer 2: bufA -> bufB (skip); xb = bf16(bufB)
  transform_kernel<<<tblocks, 256, 0, stream>>>(xb, W2, hr, nN);
  gather_kernel<<<gblocks, 256, 0, stream>>>(hr, edgebuf, offs, deg, bufA,
                                             bufB, xb, nN);

  // ---- layer 3: bufB -> bufA (skip); final (no xb needed)
  transform_kernel<<<tblocks, 256, 0, stream>>>(xb, W3, hr, nN);
  gather_kernel<<<gblocks, 256, 0, stream>>>(hr, edgebuf, offs, deg, bufB,
                                             bufA, nullptr, nN);

  // ---- heads
  heads_kernel<<<tblocks, 256, 0, stream>>>(bufA, Wa, ba, Wb, bb, (float*)d_out, nN);
}

// Round 12
// 281.570 us; speedup vs baseline: 2.4260x; 1.0941x over previous
//
#include <hip/hip_runtime.h>

#define D 64
#define NREL 3
#define SRC_MASK 0x07FFFFFF
#define ATHR 512
#define APT 8
#define ABLK (ATHR * APT)  // 4096 edges per block for edge-pass kernels

typedef unsigned short bf16_t;
typedef __attribute__((ext_vector_type(8))) short short8v;   // 8 bf16 = 4 VGPRs
typedef __attribute__((ext_vector_type(4))) float float4v;

__device__ __forceinline__ float bf2f(unsigned int u16) {
  return __uint_as_float(u16 << 16);
}
__device__ __forceinline__ unsigned int f2bf(float f) {
  unsigned int x = __float_as_uint(f);
  return (x + 0x7fffu + ((x >> 16) & 1u)) >> 16;  // round-to-nearest-even
}

// ---------------- f32 -> bf16 convert (for layer-1 input) ----------------
__global__ __launch_bounds__(256) void conv_kernel(
    const float* __restrict__ in, bf16_t* __restrict__ out, int n4) {
  const int i = blockIdx.x * 256 + threadIdx.x;
  if (i >= n4) return;
  const float4 f = reinterpret_cast<const float4*>(in)[i];
  uint2 o;
  o.x = f2bf(f.x) | (f2bf(f.y) << 16);
  o.y = f2bf(f.z) | (f2bf(f.w) << 16);
  reinterpret_cast<uint2*>(out)[i] = o;
}

// ---------------- transform via MFMA (R11-verified: 4x faster than VALU) ----------
__global__ __launch_bounds__(256) void transform_kernel(
    const bf16_t* __restrict__ xb, const float* __restrict__ W,
    bf16_t* __restrict__ hr, int n_nodes) {
  __shared__ bf16_t wt[NREL * 64 * 72];  // 27.6 KB
  const int tid = threadIdx.x;

  for (int idx = tid; idx < NREL * 64 * 64; idx += 256) {
    const int r = idx >> 12;
    const int k = (idx >> 6) & 63;
    const int od = idx & 63;
    wt[(r * 64 + od) * 72 + k] = (bf16_t)f2bf(W[idx]);
  }
  __syncthreads();

  const int wid = tid >> 6;
  const int lane = tid & 63;
  const int n0 = blockIdx.x * 64 + wid * 16;
  if (n0 >= n_nodes) return;

  const bf16_t* xrow = &xb[(long)(n0 + (lane & 15)) * 64 + (lane >> 4) * 8];
  const short8v bx0 = *reinterpret_cast<const short8v*>(xrow);
  const short8v bx1 = *reinterpret_cast<const short8v*>(xrow + 32);

  const int node = n0 + (lane & 15);
#pragma unroll
  for (int r = 0; r < NREL; ++r) {
#pragma unroll
    for (int t = 0; t < 4; ++t) {
      const bf16_t* wrow =
          &wt[(r * 64 + t * 16 + (lane & 15)) * 72 + (lane >> 4) * 8];
      const short8v a0 = *reinterpret_cast<const short8v*>(wrow);
      const short8v a1 = *reinterpret_cast<const short8v*>(wrow + 32);
      float4v acc = {0.f, 0.f, 0.f, 0.f};
      acc = __builtin_amdgcn_mfma_f32_16x16x32_bf16(a0, bx0, acc, 0, 0, 0);
      acc = __builtin_amdgcn_mfma_f32_16x16x32_bf16(a1, bx1, acc, 0, 0, 0);
      const int od = t * 16 + (lane >> 4) * 4;
      uint2 o;
      o.x = f2bf(acc[0]) | (f2bf(acc[1]) << 16);
      o.y = f2bf(acc[2]) | (f2bf(acc[3]) << 16);
      *reinterpret_cast<uint2*>(&hr[((long)r * n_nodes + node) * 64 + od]) = o;
    }
  }
}

// ---------------- CSR build (bucket-level only; no node-level atomics) ----------
// Bucket histogram: 391 counters, block-LDS counting -> ~115K L2 atomics total
// (replaces R11's hist_kernel: 1.2M node atomics, 37 MB WRITE, 50 us).
__global__ __launch_bounds__(ATHR) void bhist_kernel(
    const int* __restrict__ dst, int* __restrict__ bdeg, int n_edges, int nb) {
  __shared__ int cnt[400];
  const int t = threadIdx.x;
  for (int b = t; b < nb; b += ATHR) cnt[b] = 0;
  __syncthreads();
  const long e0 = (long)blockIdx.x * ABLK;
#pragma unroll
  for (int i = 0; i < APT; ++i) {
    const long e = e0 + t + (long)i * ATHR;
    if (e < n_edges) atomicAdd(&cnt[dst[e] >> 8], 1);
  }
  __syncthreads();
  for (int b = t; b < nb; b += ATHR)
    if (cnt[b]) atomicAdd(&bdeg[b], cnt[b]);
}

// Single block: exclusive scan of bdeg[nb] -> boffs[nb+1] (nb <= 512).
__global__ __launch_bounds__(512) void bscan_kernel(
    const int* __restrict__ bdeg, int* __restrict__ boffs, int nb) {
  __shared__ int s[512];
  const int t = threadIdx.x;
  const int v = (t < nb) ? bdeg[t] : 0;
  s[t] = v;
  __syncthreads();
  for (int off = 1; off < 512; off <<= 1) {
    const int add = (t >= off) ? s[t - off] : 0;
    __syncthreads();
    s[t] += add;
    __syncthreads();
  }
  if (t < nb) boffs[t] = s[t] - v;
  if (t == 511) boffs[nb] = s[nb - 1] + 0;  // s[nb-1] is inclusive total
}

// Phase A: bin edges by dst>>8 into the bucket's final CSR range (unordered
// within bucket). Per-block LDS counting -> ONE reserve atomic per (block,bucket).
__global__ __launch_bounds__(ATHR) void binA_kernel(
    const int* __restrict__ src, const int* __restrict__ dst,
    const int* __restrict__ rel, const float* __restrict__ norm,
    const int* __restrict__ boffs, int* __restrict__ bcur,
    int2* __restrict__ binpay, unsigned char* __restrict__ bindst,
    int n_edges, int nb) {
  __shared__ int cnt[400];
  __shared__ int basea[400];
  const int t = threadIdx.x;
  const long e0 = (long)blockIdx.x * ABLK;

  for (int b = t; b < nb; b += ATHR) cnt[b] = 0;
  __syncthreads();

  int2 pay[APT];
  int bk[APT], slot[APT], dlo[APT];
#pragma unroll
  for (int i = 0; i < APT; ++i) {
    const long e = e0 + t + (long)i * ATHR;
    if (e < n_edges) {
      const int d = dst[e];
      bk[i] = d >> 8;
      dlo[i] = d & 255;
      pay[i] = make_int2(src[e] | (rel[e] << 27), __float_as_int(norm[e]));
      slot[i] = atomicAdd(&cnt[bk[i]], 1);
    } else {
      bk[i] = -1;
    }
  }
  __syncthreads();

  for (int b = t; b < nb; b += ATHR) {
    const int c = cnt[b];
    basea[b] = c ? (boffs[b] + atomicAdd(&bcur[b], c)) : 0;
  }
  __syncthreads();

#pragma unroll
  for (int i = 0; i < APT; ++i) {
    if (bk[i] >= 0) {
      const int pos = basea[bk[i]] + slot[i];
      binpay[pos] = pay[i];
      bindst[pos] = (unsigned char)dlo[i];
    }
  }
}

// Phase B: one block per bucket. Pass 1: count per-node edges in LDS, LDS
// exclusive scan -> write deg/offs to global (for gather). Pass 2: place
// edges at exact CSR position via LDS cursors. No global atomics.
__global__ __launch_bounds__(256) void binB_kernel(
    const int2* __restrict__ binpay, const unsigned char* __restrict__ bindst,
    const int* __restrict__ boffs, int2* __restrict__ edgebuf,
    int* __restrict__ deg, int* __restrict__ offs, int n_nodes) {
  __shared__ int cnt[256];
  __shared__ int ss[256];
  __shared__ int cur[256];
  const int b = blockIdx.x;
  const int t = threadIdx.x;
  cnt[t] = 0;
  __syncthreads();
  const int start = boffs[b];
  const int end = boffs[b + 1];
  for (int i = start + t; i < end; i += 256) atomicAdd(&cnt[bindst[i]], 1);
  __syncthreads();
  const int v = cnt[t];
  ss[t] = v;
  __syncthreads();
  for (int off = 1; off < 256; off <<= 1) {
    const int add = (t >= off) ? ss[t - off] : 0;
    __syncthreads();
    ss[t] += add;
    __syncthreads();
  }
  const int excl = ss[t] - v;
  cur[t] = excl;
  const int node = (b << 8) + t;
  if (node < n_nodes) {
    deg[node] = v;
    offs[node] = start + excl;
  }
  __syncthreads();
  for (int i = start + t; i < end; i += 256) {
    const int dl = bindst[i];
    const int pos = start + atomicAdd(&cur[dl], 1);
    edgebuf[pos] = binpay[i];
  }
}

// ---------------- fused gather + skip + relu (bf16 hr), 4-deep MLP ----------------
__global__ __launch_bounds__(256) void gather_kernel(
    const bf16_t* __restrict__ hr, const int2* __restrict__ edgebuf,
    const int* __restrict__ offs, const int* __restrict__ deg,
    const float* __restrict__ skip, float* __restrict__ out,
    bf16_t* __restrict__ xbout, int n_nodes) {
  const long gid = (long)blockIdx.x * 256 + threadIdx.x;
  const int n = (int)(gid >> 4);
  if (n >= n_nodes) return;
  const int c = (int)(gid & 15) * 4;

  const int beg = offs[n];
  const int cnt = deg[n];

  float4 acc0 = {0.f, 0.f, 0.f, 0.f};
  float4 acc1 = {0.f, 0.f, 0.f, 0.f};
  int i = 0;
  for (; i + 3 < cnt; i += 4) {
    const int2 e0 = edgebuf[beg + i];
    const int2 e1 = edgebuf[beg + i + 1];
    const int2 e2 = edgebuf[beg + i + 2];
    const int2 e3 = edgebuf[beg + i + 3];
    const uint2 v0 = *reinterpret_cast<const uint2*>(
        &hr[((long)(((unsigned)e0.x) >> 27) * n_nodes + (e0.x & SRC_MASK)) * 64 + c]);
    const uint2 v1 = *reinterpret_cast<const uint2*>(
        &hr[((long)(((unsigned)e1.x) >> 27) * n_nodes + (e1.x & SRC_MASK)) * 64 + c]);
    const uint2 v2 = *reinterpret_cast<const uint2*>(
        &hr[((long)(((unsigned)e2.x) >> 27) * n_nodes + (e2.x & SRC_MASK)) * 64 + c]);
    const uint2 v3 = *reinterpret_cast<const uint2*>(
        &hr[((long)(((unsigned)e3.x) >> 27) * n_nodes + (e3.x & SRC_MASK)) * 64 + c]);
    const float n0 = __int_as_float(e0.y), n1 = __int_as_float(e1.y);
    const float n2 = __int_as_float(e2.y), n3 = __int_as_float(e3.y);
    acc0.x += bf2f(v0.x & 0xffff) * n0; acc0.y += bf2f(v0.x >> 16) * n0;
    acc0.z += bf2f(v0.y & 0xffff) * n0; acc0.w += bf2f(v0.y >> 16) * n0;
    acc1.x += bf2f(v1.x & 0xffff) * n1; acc1.y += bf2f(v1.x >> 16) * n1;
    acc1.z += bf2f(v1.y & 0xffff) * n1; acc1.w += bf2f(v1.y >> 16) * n1;
    acc0.x += bf2f(v2.x & 0xffff) * n2; acc0.y += bf2f(v2.x >> 16) * n2;
    acc0.z += bf2f(v2.y & 0xffff) * n2; acc0.w += bf2f(v2.y >> 16) * n2;
    acc1.x += bf2f(v3.x & 0xffff) * n3; acc1.y += bf2f(v3.x >> 16) * n3;
    acc1.z += bf2f(v3.y & 0xffff) * n3; acc1.w += bf2f(v3.y >> 16) * n3;
  }
  for (; i < cnt; ++i) {
    const int2 ea = edgebuf[beg + i];
    const float na = __int_as_float(ea.y);
    const uint2 va = *reinterpret_cast<const uint2*>(
        &hr[((long)(((unsigned)ea.x) >> 27) * n_nodes + (ea.x & SRC_MASK)) * 64 + c]);
    acc0.x += bf2f(va.x & 0xffff) * na; acc0.y += bf2f(va.x >> 16) * na;
    acc0.z += bf2f(va.y & 0xffff) * na; acc0.w += bf2f(va.y >> 16) * na;
  }
  float4 a;
  a.x = acc0.x + acc1.x; a.y = acc0.y + acc1.y;
  a.z = acc0.z + acc1.z; a.w = acc0.w + acc1.w;
  if (skip != nullptr) {
    const float4 s = *reinterpret_cast<const float4*>(&skip[(long)n * 64 + c]);
    a.x += s.x; a.y += s.y; a.z += s.z; a.w += s.w;
  }
  a.x = fmaxf(a.x, 0.f); a.y = fmaxf(a.y, 0.f);
  a.z = fmaxf(a.z, 0.f); a.w = fmaxf(a.w, 0.f);
  *reinterpret_cast<float4*>(&out[(long)n * 64 + c]) = a;
  if (xbout != nullptr) {
    uint2 o;
    o.x = f2bf(a.x) | (f2bf(a.y) << 16);
    o.y = f2bf(a.z) | (f2bf(a.w) << 16);
    *reinterpret_cast<uint2*>(&xbout[(long)n * 64 + c]) = o;
  }
}

// ---------------- heads ----------------
__global__ __launch_bounds__(256) void heads_kernel(
    const float* __restrict__ x, const float* __restrict__ Wa,
    const float* __restrict__ ba, const float* __restrict__ Wb,
    const float* __restrict__ bb, float* __restrict__ out, int n_nodes) {
  __shared__ float xs[64][65];
  __shared__ float wlt[64][24];  // [k][s], padded to 24
  __shared__ float bl[23];
  const int tid = threadIdx.x;
  const int base = blockIdx.x * 64;

  for (int idx = tid; idx < 2 * 64; idx += 256)
    wlt[idx & 63][idx >> 6] = Wa[idx];
  for (int idx = tid; idx < 21 * 64; idx += 256)
    wlt[idx & 63][2 + (idx >> 6)] = Wb[idx];
  if (tid < 2) bl[tid] = ba[tid];
  else if (tid < 23) bl[tid] = bb[tid - 2];
  const int nrows = min(64, n_nodes - base);
  for (int idx = tid; idx < nrows * 64; idx += 256)
    xs[idx >> 6][idx & 63] = x[(long)base * 64 + idx];
  __syncthreads();

  for (int idx = tid; idx < nrows * 23; idx += 256) {
    const int n = idx / 23;
    const int s = idx % 23;
    float acc = 0.f;
#pragma unroll
    for (int k = 0; k < 64; ++k) acc += xs[n][k] * wlt[k][s];
    acc += bl[s];
    const long node = base + n;
    if (s < 2) out[node * 2 + s] = acc;
    else out[(long)n_nodes * 2 + node * 21 + (s - 2)] = acc;
  }
}

static inline char* align_up(char* p, size_t a) {
  return (char*)(((uintptr_t)p + a - 1) & ~(uintptr_t)(a - 1));
}

extern "C" void kernel_launch(void* const* d_in, const int* in_sizes, int n_in,
                              void* d_out, int out_size, void* d_ws, size_t ws_size,
                              hipStream_t stream) {
  const float* v    = (const float*)d_in[0];
  const int*   esrc = (const int*)d_in[1];
  const int*   edst = (const int*)d_in[2];
  const int*   erel = (const int*)d_in[3];
  const float* norm = (const float*)d_in[4];
  const float* W1   = (const float*)d_in[5];
  const float* W2   = (const float*)d_in[6];
  const float* W3   = (const float*)d_in[7];
  const float* Wa   = (const float*)d_in[8];
  const float* ba   = (const float*)d_in[9];
  const float* Wb   = (const float*)d_in[10];
  const float* bb   = (const float*)d_in[11];

  const int nN = in_sizes[0] / D;  // 100000
  const int E  = in_sizes[1];      // 1200000
  const int nb = (nN + 255) >> 8;  // 256-node buckets

  // ---- workspace layout
  char* p = (char*)d_ws;
  bf16_t* hr = (bf16_t*)p;            p += 3L * nN * D * sizeof(bf16_t);
  p = align_up(p, 16);
  bf16_t* xb = (bf16_t*)p;            p += (long)nN * D * sizeof(bf16_t);
  p = align_up(p, 16);
  float* bufA = (float*)p;            p += (long)nN * D * sizeof(float);
  float* bufB = (float*)p;            p += (long)nN * D * sizeof(float);
  int* deg      = (int*)p;            p += (long)nN * sizeof(int);
  int* offs     = (int*)p;            p += (long)nN * sizeof(int);
  int* bdeg     = (int*)p;            p += (long)nb * sizeof(int);
  int* boffs    = (int*)p;            p += (long)(nb + 1) * sizeof(int);
  int* bcur     = (int*)p;            p += (long)nb * sizeof(int);
  p = align_up(p, 16);
  int2* edgebuf = (int2*)p;           p += (long)E * sizeof(int2);
  int2* binpay  = (int2*)p;           p += (long)E * sizeof(int2);
  unsigned char* bindst = (unsigned char*)p;  p += (long)E;

  const int tblocks = (nN + 63) / 64;
  const int gblocks = (int)(((long)nN * 16 + 255) / 256);
  const int ablocks = (E + ABLK - 1) / ABLK;
  const int cblocks = (nN * D / 4 + 255) / 256;

  // ---- CSR build (bucket-level histogram only; once per call)
  hipMemsetAsync(bdeg, 0, (size_t)nb * sizeof(int), stream);
  hipMemsetAsync(bcur, 0, (size_t)nb * sizeof(int), stream);
  bhist_kernel<<<ablocks, ATHR, 0, stream>>>(edst, bdeg, E, nb);
  bscan_kernel<<<1, 512, 0, stream>>>(bdeg, boffs, nb);
  binA_kernel<<<ablocks, ATHR, 0, stream>>>(esrc, edst, erel, norm, boffs, bcur,
                                            binpay, bindst, E, nb);
  binB_kernel<<<nb, 256, 0, stream>>>(binpay, bindst, boffs, edgebuf, deg, offs, nN);

  // ---- layer 1: v -> bufA (no skip); xb = bf16(v)
  conv_kernel<<<cblocks, 256, 0, stream>>>(v, xb, nN * D / 4);
  transform_kernel<<<tblocks, 256, 0, stream>>>(xb, W1, hr, nN);
  gather_kernel<<<gblocks, 256, 0, stream>>>(hr, edgebuf, offs, deg, nullptr,
                                             bufA, xb, nN);

  // ---- layer 2: bufA -> bufB (skip); xb = bf16(bufB)
  transform_kernel<<<tblocks, 256, 0, stream>>>(xb, W2, hr, nN);
  gather_kernel<<<gblocks, 256, 0, stream>>>(hr, edgebuf, offs, deg, bufA,
                                             bufB, xb, nN);

  // ---- layer 3: bufB -> bufA (skip); final (no xb needed)
  transform_kernel<<<tblocks, 256, 0, stream>>>(xb, W3, hr, nN);
  gather_kernel<<<gblocks, 256, 0, stream>>>(hr, edgebuf, offs, deg, bufB,
                                             bufA, nullptr, nN);

  // ---- heads
  heads_kernel<<<tblocks, 256, 0, stream>>>(bufA, Wa, ba, Wb, bb, (float*)d_out, nN);
}